// Round 5
// baseline (481.388 us; speedup 1.0000x reference)
//
#include <hip/hip_runtime.h>
#include <stdint.h>

// CrossAttention via linear-attention algebra, both halves merged to M=16384:
//   S = K1^T V1 + K2^T V2 (per b,h; 64x64), shared by both halves.
//   attn = Q @ S ; x = LN(inp + attn@Wo^T + bo) ; out = LN(x + FF(x))
// bf16 MFMA GEMMs. M-major grids (row-band stays on one XCD -> A fetched once).
// Wide 128x256 tiles for QKV/FFN1 (32 MFMA per barrier-pair per wave).
// FFN2: full-M, K=2048, epilogue fuses +b2+x residual, bf16 in-place. No split-K.

#define Bq 4
#define Lq 2048
#define Dq 512
#define PFq 2048
#define Mrows 16384
#define MiBu 1048576ull

typedef __attribute__((ext_vector_type(8))) short frag_ab;
typedef __attribute__((ext_vector_type(4))) float frag_cd;

__device__ __forceinline__ unsigned short f2b(float f) {
    union { float f; uint32_t u; } x; x.f = f;
    uint32_t r = x.u + 0x7fffu + ((x.u >> 16) & 1u);
    return (unsigned short)(r >> 16);
}
__device__ __forceinline__ float b2f(unsigned short u) {
    union { uint32_t u; float f; } x; x.u = ((uint32_t)u) << 16;
    return x.f;
}

#define GLD16(g, l)                                                              \
    __builtin_amdgcn_global_load_lds(                                            \
        (const __attribute__((address_space(1))) void*)(const void*)(g),         \
        (__attribute__((address_space(3))) void*)(void*)(l), 16, 0, 0)

// ---------- wide GEMM: out_b = A[M,K]b @ W[N,K]b^T + bias (+relu), BM=128 BN=256
// grid (M/128, N/256), block 256; wave w: rows (w&1)*64, cols (w>>1)*128
__global__ __launch_bounds__(256) void gemm_wide(
    const unsigned short* __restrict__ A, const unsigned short* __restrict__ Wt,
    const float* __restrict__ bias, unsigned short* __restrict__ outB,
    int M, int N, int K, int relu)
{
    __shared__ __align__(16) unsigned short At[128 * 32];
    __shared__ __align__(16) unsigned short Bt[256 * 32];
    const int tid = threadIdx.x;
    const int lane = tid & 63;
    const int w = tid >> 6;
    const int wm = (w & 1) * 64, wn = (w >> 1) * 128;
    const int lr = lane & 15;
    const int quad = lane >> 4;
    const size_t bm = (size_t)blockIdx.x * 128, bn = (size_t)blockIdx.y * 256;

    frag_cd acc[4][8] = {};

    const int e = tid * 8;
    const int ar = e >> 5, ac = e & 31;           // 64 rows x 32 cols per issue
    const unsigned short* Ag  = A  + (bm + ar) * (size_t)K + ac;
    const unsigned short* Ag2 = Ag + (size_t)64 * K;
    const unsigned short* Bg  = Wt + (bn + ar) * (size_t)K + ac;
    const unsigned short* Bg2 = Bg + (size_t)64 * K;
    const unsigned short* Bg3 = Bg + (size_t)128 * K;
    const unsigned short* Bg4 = Bg + (size_t)192 * K;
    unsigned short* Asd = At + w * 512;
    unsigned short* Bsd = Bt + w * 512;

    for (int k0 = 0; k0 < K; k0 += 32) {
        __syncthreads();
        GLD16(Ag  + k0, Asd);
        GLD16(Ag2 + k0, Asd + 2048);
        GLD16(Bg  + k0, Bsd);
        GLD16(Bg2 + k0, Bsd + 2048);
        GLD16(Bg3 + k0, Bsd + 4096);
        GLD16(Bg4 + k0, Bsd + 6144);
        __syncthreads();
        frag_ab a[4], b[8];
#pragma unroll
        for (int i = 0; i < 4; ++i)
            a[i] = *(const frag_ab*)&At[(wm + i * 16 + lr) * 32 + quad * 8];
#pragma unroll
        for (int j = 0; j < 8; ++j)
            b[j] = *(const frag_ab*)&Bt[(wn + j * 16 + lr) * 32 + quad * 8];
#pragma unroll
        for (int i = 0; i < 4; ++i)
#pragma unroll
            for (int j = 0; j < 8; ++j)
                acc[i][j] = __builtin_amdgcn_mfma_f32_16x16x32_bf16(a[i], b[j], acc[i][j], 0, 0, 0);
    }

#pragma unroll
    for (int j = 0; j < 8; ++j) {
        const int col = (int)bn + wn + j * 16 + lr;
        const float bv = bias[col];
#pragma unroll
        for (int i = 0; i < 4; ++i) {
            const int rowb = (int)bm + wm + i * 16 + quad * 4;
#pragma unroll
            for (int r = 0; r < 4; ++r) {
                float v = acc[i][j][r] + bv;
                if (relu) v = fmaxf(v, 0.f);
                outB[(size_t)(rowb + r) * N + col] = f2b(v);
            }
        }
    }
}

// ---------- residual GEMM: BM=128 BN=128, out_b = A@W^T + bias + residual ------
// resA/resB f32 (rows <8192 / >=8192). If resA==null: residual = b2f(outB[idx])
// (in-place). grid (M/128, N/128).
__global__ __launch_bounds__(256) void gemm_res(
    const unsigned short* __restrict__ A, const unsigned short* __restrict__ Wt,
    const float* __restrict__ bias,
    const float* __restrict__ resA, const float* __restrict__ resB,
    unsigned short* __restrict__ outB, int M, int N, int K)
{
    __shared__ __align__(16) unsigned short At[128 * 32];
    __shared__ __align__(16) unsigned short Bt[128 * 32];
    const int tid = threadIdx.x;
    const int lane = tid & 63;
    const int w = tid >> 6;
    const int wm = (w >> 1) * 64, wn = (w & 1) * 64;
    const int lr = lane & 15;
    const int quad = lane >> 4;
    const size_t bm = (size_t)blockIdx.x * 128, bn = (size_t)blockIdx.y * 128;

    frag_cd acc[4][4] = {};

    const int e = tid * 8;
    const int ar = e >> 5, ac = e & 31;
    const unsigned short* Ag  = A  + (bm + ar) * (size_t)K + ac;
    const unsigned short* Ag2 = Ag + (size_t)64 * K;
    const unsigned short* Bg  = Wt + (bn + ar) * (size_t)K + ac;
    const unsigned short* Bg2 = Bg + (size_t)64 * K;
    unsigned short* Asd = At + w * 512;
    unsigned short* Bsd = Bt + w * 512;

    for (int k0 = 0; k0 < K; k0 += 32) {
        __syncthreads();
        GLD16(Ag  + k0, Asd);
        GLD16(Ag2 + k0, Asd + 2048);
        GLD16(Bg  + k0, Bsd);
        GLD16(Bg2 + k0, Bsd + 2048);
        __syncthreads();
        frag_ab a[4], b[4];
#pragma unroll
        for (int i = 0; i < 4; ++i)
            a[i] = *(const frag_ab*)&At[(wm + i * 16 + lr) * 32 + quad * 8];
#pragma unroll
        for (int j = 0; j < 4; ++j)
            b[j] = *(const frag_ab*)&Bt[(wn + j * 16 + lr) * 32 + quad * 8];
#pragma unroll
        for (int i = 0; i < 4; ++i)
#pragma unroll
            for (int j = 0; j < 4; ++j)
                acc[i][j] = __builtin_amdgcn_mfma_f32_16x16x32_bf16(a[i], b[j], acc[i][j], 0, 0, 0);
    }

#pragma unroll
    for (int j = 0; j < 4; ++j) {
        const int col = (int)bn + wn + j * 16 + lr;
        const float bv = bias[col];
#pragma unroll
        for (int i = 0; i < 4; ++i) {
            const int rowb = (int)bm + wm + i * 16 + quad * 4;
#pragma unroll
            for (int r = 0; r < 4; ++r) {
                const int row = rowb + r;
                const size_t idx = (size_t)row * N + col;
                float v = acc[i][j][r] + bv;
                if (resA)
                    v += (row < 8192) ? resA[idx] : resB[idx - (size_t)8192 * N];
                else
                    v += b2f(outB[idx]);
                outB[idx] = f2b(v);
            }
        }
    }
}

// -------- merged fp32->bf16 converts + S zero + QKV bias concat --------
__global__ __launch_bounds__(256) void convert_all(
    const float* __restrict__ Wq, const float* __restrict__ Wk,
    const float* __restrict__ Wv, const float* __restrict__ Wo,
    const float* __restrict__ W1, const float* __restrict__ W2,
    const float* __restrict__ question, const float* __restrict__ query,
    const float* __restrict__ bqp, const float* __restrict__ bkp,
    const float* __restrict__ bvp,
    unsigned short* __restrict__ Wqkvb, unsigned short* __restrict__ Wob,
    unsigned short* __restrict__ W1b, unsigned short* __restrict__ W2b,
    unsigned short* __restrict__ Xb, float* __restrict__ S,
    float* __restrict__ bqkv)
{
    const int b = blockIdx.x;
    const float* src; unsigned short* dst; size_t off;
    if (b < 256)        { src = Wq; dst = Wqkvb;          off = (size_t)b * 1024; }
    else if (b < 512)   { src = Wk; dst = Wqkvb + 262144; off = (size_t)(b - 256) * 1024; }
    else if (b < 768)   { src = Wv; dst = Wqkvb + 524288; off = (size_t)(b - 512) * 1024; }
    else if (b < 1024)  { src = Wo; dst = Wob;            off = (size_t)(b - 768) * 1024; }
    else if (b < 2048)  { src = W1; dst = W1b;            off = (size_t)(b - 1024) * 1024; }
    else if (b < 3072)  { src = W2; dst = W2b;            off = (size_t)(b - 2048) * 1024; }
    else if (b < 7168)  { src = question; dst = Xb;       off = (size_t)(b - 3072) * 1024; }
    else if (b < 11264) { src = query; dst = Xb + 4194304; off = (size_t)(b - 7168) * 1024; }
    else if (b < 11392) {
        const size_t idx = ((size_t)(b - 11264) * 256 + threadIdx.x) * 4;
        *(float4*)(S + idx) = make_float4(0.f, 0.f, 0.f, 0.f);
        return;
    } else {
        const int n = (b - 11392) * 256 + threadIdx.x;
        bqkv[n] = (n < 512) ? bqp[n] : (n < 1024) ? bkp[n - 512] : bvp[n - 1024];
        return;
    }
    const size_t idx = off + threadIdx.x * 4;
    float4 v = *(const float4*)(src + idx);
    ushort4 o;
    o.x = f2b(v.x); o.y = f2b(v.y); o.z = f2b(v.z); o.w = f2b(v.w);
    *(ushort4*)(dst + idx) = o;
}

// ------- S[b,h] += sum over both halves of K^T outer V (merged QKV) -------
__global__ __launch_bounds__(256) void s_kernel(
    const unsigned short* __restrict__ QKV, float* __restrict__ S)
{
    const int bh = blockIdx.x, chunk = blockIdx.y;
    const int b = bh >> 3, h = bh & 7;
    __shared__ float Ks[8][64];
    __shared__ float Vs[8][64];
    const int tid = threadIdx.x;
    const int tx = tid & 15, ty = tid >> 4;
    float acc[4][4] = {};
    for (int pass = 0; pass < 2; ++pass) {
        for (int l0 = 0; l0 < 128; l0 += 8) {
#pragma unroll
            for (int it = 0; it < 2; ++it) {
                const int e = tid + it * 256;
                const int rr = e >> 6, cc = e & 63;
                const size_t row = (size_t)pass * 8192 + (size_t)b * Lq + chunk * 128 + l0 + rr;
                Ks[rr][cc] = b2f(QKV[row * 1536 + 512 + h * 64 + cc]);
                Vs[rr][cc] = b2f(QKV[row * 1536 + 1024 + h * 64 + cc]);
            }
            __syncthreads();
#pragma unroll
            for (int rr = 0; rr < 8; ++rr) {
                float kv[4], vv[4];
#pragma unroll
                for (int i = 0; i < 4; ++i) kv[i] = Ks[rr][ty * 4 + i];
#pragma unroll
                for (int j = 0; j < 4; ++j) vv[j] = Vs[rr][tx * 4 + j];
#pragma unroll
                for (int i = 0; i < 4; ++i)
#pragma unroll
                    for (int j = 0; j < 4; ++j)
                        acc[i][j] = fmaf(kv[i], vv[j], acc[i][j]);
            }
            __syncthreads();
        }
    }
#pragma unroll
    for (int i = 0; i < 4; ++i)
#pragma unroll
        for (int j = 0; j < 4; ++j)
            atomicAdd(&S[((size_t)bh * 64 + ty * 4 + i) * 64 + tx * 4 + j], acc[i][j]);
}

// ------- S fp32 -> Sbt bf16, B-operand layout [bh][khalf][n][kj] -------
__global__ __launch_bounds__(256) void sbt_convert(
    const float* __restrict__ S, unsigned short* __restrict__ Sbt)
{
    const int bh = blockIdx.x;
    const float* Sp = S + (size_t)bh * 4096;
    unsigned short* Dp = Sbt + (size_t)bh * 4096;
    const int t = threadIdx.x;
#pragma unroll
    for (int u = 0; u < 16; ++u) {
        const int d = t * 16 + u;
        const int kj = d & 31, n = (d >> 5) & 63, kk = d >> 11;
        Dp[d] = f2b(Sp[(size_t)(kk * 32 + kj) * 64 + n]);
    }
}

// ------- attn = Q @ S_bh via MFMA; block: 128 rows x 64 cols (one head) -------
__global__ __launch_bounds__(256) void attn_mfma(
    const unsigned short* __restrict__ QKV, const unsigned short* __restrict__ Sbt,
    unsigned short* __restrict__ Ob)
{
    __shared__ __align__(16) unsigned short At[2 * 128 * 32];
    __shared__ __align__(16) unsigned short Bt[2 * 64 * 32];
    const int h = blockIdx.x;
    const int rbase = blockIdx.y * 128;
    const int b = (rbase >> 11) & 3;
    const int bh = b * 8 + h;
    const int tid = threadIdx.x;
    const int lane = tid & 63;
    const int w = tid >> 6;
    const int lr = lane & 15;
    const int quad = lane >> 4;

    {
        const int rloc = tid >> 2, c8 = (tid & 3) * 8;
#pragma unroll
        for (int it = 0; it < 4; ++it) {
            const int kk = it & 1, rh = it >> 1;
            const unsigned short* g = QKV +
                ((size_t)rbase + rh * 64 + rloc) * 1536 + h * 64 + kk * 32 + c8;
            GLD16(g, At + kk * 4096 + rh * 2048 + w * 512);
        }
        const unsigned short* Sg = Sbt + (size_t)bh * 4096 + tid * 8;
#pragma unroll
        for (int bi = 0; bi < 2; ++bi)
            GLD16(Sg + bi * 2048, Bt + bi * 2048 + w * 512);
    }
    __syncthreads();

    frag_cd acc[2][4] = {};
#pragma unroll
    for (int kk = 0; kk < 2; ++kk) {
        frag_ab a[2], bfr[4];
#pragma unroll
        for (int i = 0; i < 2; ++i)
            a[i] = *(const frag_ab*)&At[kk * 4096 + (w * 32 + i * 16 + lr) * 32 + quad * 8];
#pragma unroll
        for (int j = 0; j < 4; ++j)
            bfr[j] = *(const frag_ab*)&Bt[kk * 2048 + (j * 16 + lr) * 32 + quad * 8];
#pragma unroll
        for (int i = 0; i < 2; ++i)
#pragma unroll
            for (int j = 0; j < 4; ++j)
                acc[i][j] = __builtin_amdgcn_mfma_f32_16x16x32_bf16(a[i], bfr[j], acc[i][j], 0, 0, 0);
    }

#pragma unroll
    for (int i = 0; i < 2; ++i) {
        const int rowb = rbase + w * 32 + i * 16 + quad * 4;
#pragma unroll
        for (int j = 0; j < 4; ++j) {
            const int col = h * 64 + j * 16 + lr;
#pragma unroll
            for (int r = 0; r < 4; ++r)
                Ob[(size_t)(rowb + r) * 512 + col] = f2b(acc[i][j][r]);
        }
    }
}

// ------- LN over bf16 row (512) in place -------
__global__ __launch_bounds__(256) void ln_b16_inplace(
    unsigned short* __restrict__ Y, const float* __restrict__ g,
    const float* __restrict__ bta)
{
    __shared__ float red[256];
    const int row = blockIdx.x;
    const int t = threadIdx.x;
    unsigned short* yr = Y + (size_t)row * Dq;
    float v0 = b2f(yr[t]), v1 = b2f(yr[t + 256]);
    red[t] = v0 + v1;
    __syncthreads();
    for (int s = 128; s > 0; s >>= 1) { if (t < s) red[t] += red[t + s]; __syncthreads(); }
    const float mean = red[0] * (1.f / Dq);
    __syncthreads();
    const float d0 = v0 - mean, d1 = v1 - mean;
    red[t] = d0 * d0 + d1 * d1;
    __syncthreads();
    for (int s = 128; s > 0; s >>= 1) { if (t < s) red[t] += red[t + s]; __syncthreads(); }
    const float rstd = rsqrtf(red[0] * (1.f / Dq) + 1e-5f);
    yr[t] = f2b(d0 * rstd * g[t] + bta[t]);
    yr[t + 256] = f2b(d1 * rstd * g[t + 256] + bta[t + 256]);
}

// ------- LN over bf16 row -> out f32 half-columns (merged rows) -------
__global__ __launch_bounds__(256) void ln_b16_out(
    const unsigned short* __restrict__ Y, const float* __restrict__ g,
    const float* __restrict__ bta, float* __restrict__ out)
{
    __shared__ float red[256];
    const int row = blockIdx.x;
    const int t = threadIdx.x;
    const unsigned short* yr = Y + (size_t)row * Dq;
    float v0 = b2f(yr[t]), v1 = b2f(yr[t + 256]);
    red[t] = v0 + v1;
    __syncthreads();
    for (int s = 128; s > 0; s >>= 1) { if (t < s) red[t] += red[t + s]; __syncthreads(); }
    const float mean = red[0] * (1.f / Dq);
    __syncthreads();
    const float d0 = v0 - mean, d1 = v1 - mean;
    red[t] = d0 * d0 + d1 * d1;
    __syncthreads();
    for (int s = 128; s > 0; s >>= 1) { if (t < s) red[t] += red[t + s]; __syncthreads(); }
    const float rstd = rsqrtf(red[0] * (1.f / Dq) + 1e-5f);
    const int half = row >> 13, br = row & 8191;
    float* orow = out + (size_t)br * 1024 + half * 512;
    orow[t] = d0 * rstd * g[t] + bta[t];
    orow[t + 256] = d1 * rstd * g[t + 256] + bta[t + 256];
}

extern "C" void kernel_launch(void* const* d_in, const int* in_sizes, int n_in,
                              void* d_out, int out_size, void* d_ws, size_t ws_size,
                              hipStream_t stream)
{
    const float* question = (const float*)d_in[0];
    const float* query    = (const float*)d_in[1];
    const float* Wq = (const float*)d_in[2];  const float* bqp = (const float*)d_in[3];
    const float* Wk = (const float*)d_in[4];  const float* bkp = (const float*)d_in[5];
    const float* Wv = (const float*)d_in[6];  const float* bvp = (const float*)d_in[7];
    const float* Wo = (const float*)d_in[8];  const float* bo  = (const float*)d_in[9];
    const float* ln_g = (const float*)d_in[10]; const float* ln_b = (const float*)d_in[11];
    const float* W1 = (const float*)d_in[12]; const float* b1 = (const float*)d_in[13];
    const float* W2 = (const float*)d_in[14]; const float* b2 = (const float*)d_in[15];
    float* out = (float*)d_out;
    char* ws = (char*)d_ws;

    // ---- workspace (~87 MiB) ----
    // R0 [0,48M): QKVb bf16 [16384,1536]      -> h[0:48M) later
    // R1 [48,64M): attnb bf16 [16384,512]     -> h[48:64M) later
    // R2 [64,80M): Xb bf16 in -> y0b/xb/y bf16 (LN1 in-place; FFN2 in-place)
    // [80M,80.5M): S f32; then weights bf16 + Sbt + bqkv
    unsigned short* QKVb  = (unsigned short*)(ws);
    unsigned short* attnb = (unsigned short*)(ws + 48 * MiBu);
    unsigned short* Xb    = (unsigned short*)(ws + 64 * MiBu);
    unsigned short* xbuf  = (unsigned short*)(ws + 64 * MiBu);  // y0b -> xb -> y
    unsigned short* hb    = (unsigned short*)(ws);              // [16384,2048] bf16
    float* S = (float*)(ws + 80 * MiBu);
    char* wp = ws + 80 * MiBu + 524288;
    unsigned short* Wqkvb = (unsigned short*)wp;  wp += 1536 * 512 * 2;
    unsigned short* Wob   = (unsigned short*)wp;  wp += 512 * 512 * 2;
    unsigned short* W1b   = (unsigned short*)wp;  wp += 2048 * 512 * 2;
    unsigned short* W2b   = (unsigned short*)wp;  wp += 512 * 2048 * 2;
    unsigned short* Sbt   = (unsigned short*)wp;  wp += 32 * 4096 * 2;
    float* bqkv           = (float*)wp;

    dim3 blk(256);

    convert_all<<<11398, blk, 0, stream>>>(Wq, Wk, Wv, Wo, W1, W2, question, query,
                                           bqp, bkp, bvp,
                                           Wqkvb, Wob, W1b, W2b, Xb, S, bqkv);

    // QKV: [16384,512]@[1536,512]^T -> bf16; M-major grid, wide tiles (768 blocks)
    gemm_wide<<<dim3(128, 6), blk, 0, stream>>>(Xb, Wqkvb, bqkv, QKVb,
                                                Mrows, 1536, 512, 0);

    // S accumulation (fp32) -> bf16 B-layout; attn via MFMA (1024 blocks)
    s_kernel<<<dim3(32, 16), blk, 0, stream>>>(QKVb, S);
    sbt_convert<<<32, blk, 0, stream>>>(S, Sbt);
    attn_mfma<<<dim3(8, 128), blk, 0, stream>>>(QKVb, Sbt, attnb);

    // o-proj + residual(inputs) + bo -> bf16 y0b (512 blocks)
    gemm_res<<<dim3(128, 4), blk, 0, stream>>>(attnb, Wob, bo, question, query,
                                               xbuf, Mrows, 512, 512);

    // LN1 in place: xb = LN(y0b)
    ln_b16_inplace<<<Mrows, blk, 0, stream>>>(xbuf, ln_g, ln_b);

    // FFN1 full-M: h = relu(xb @ W1^T + b1) -> bf16 [16384,2048] (1024 blocks)
    gemm_wide<<<dim3(128, 8), blk, 0, stream>>>(xbuf, W1b, b1, hb,
                                                Mrows, PFq, 512, 1);

    // FFN2 full-M, K=2048: y = h @ W2^T + b2 + xb, bf16 in place (512 blocks)
    gemm_res<<<dim3(128, 4), blk, 0, stream>>>(hb, W2b, b2, nullptr, nullptr,
                                               xbuf, Mrows, 512, PFq);

    // LN2 -> out halves
    ln_b16_out<<<Mrows, blk, 0, stream>>>(xbuf, ln_g, ln_b, out);
}

// Round 6
// 409.831 us; speedup vs baseline: 1.1746x; 1.1746x over previous
//
#include <hip/hip_runtime.h>
#include <stdint.h>

// CrossAttention via linear-attention algebra, both halves merged to M=16384:
//   S = K1^T V1 + K2^T V2 (per b,h; 64x64), shared by both halves.
//   attn = Q @ S ; x = LN(inp + attn@Wo^T + bo) ; out = LN(x + FF(x))
// bf16 MFMA GEMMs, 128x128 tiles (3 blocks/CU — occupancy is what feeds the
// m97 structure; 256-wide tiles dropped to 1 block/CU and regressed, R5).
// M-major grids: blockIdx.x = row-tile so a row-band's N-tiles share an XCD.
// Fused epilogues: o-proj += inp + bo; FFN2 += b2 + x in place. No split-K.

#define Bq 4
#define Lq 2048
#define Dq 512
#define PFq 2048
#define Mrows 16384
#define MiBu 1048576ull

typedef __attribute__((ext_vector_type(8))) short frag_ab;
typedef __attribute__((ext_vector_type(4))) float frag_cd;

__device__ __forceinline__ unsigned short f2b(float f) {
    union { float f; uint32_t u; } x; x.f = f;
    uint32_t r = x.u + 0x7fffu + ((x.u >> 16) & 1u);
    return (unsigned short)(r >> 16);
}
__device__ __forceinline__ float b2f(unsigned short u) {
    union { uint32_t u; float f; } x; x.u = ((uint32_t)u) << 16;
    return x.f;
}

#define GLD16(g, l)                                                              \
    __builtin_amdgcn_global_load_lds(                                            \
        (const __attribute__((address_space(1))) void*)(const void*)(g),         \
        (__attribute__((address_space(3))) void*)(void*)(l), 16, 0, 0)

// ---------- bf16 MFMA GEMM: outB = A[M,K]b @ W[N,K]b^T + bias (+relu) ----------
// grid (M/128, N/128), block 256 (4 waves, each 64x64 of the 128x128 tile)
__global__ __launch_bounds__(256) void gemm_bf16(
    const unsigned short* __restrict__ A, const unsigned short* __restrict__ Wt,
    const float* __restrict__ bias, unsigned short* __restrict__ outB,
    int M, int N, int K, int relu)
{
    __shared__ __align__(16) unsigned short At[128 * 32];
    __shared__ __align__(16) unsigned short Bt[128 * 32];
    const int tid = threadIdx.x;
    const int lane = tid & 63;
    const int w = tid >> 6;
    const int wm = (w >> 1) * 64, wn = (w & 1) * 64;
    const int lr = lane & 15;
    const int quad = lane >> 4;
    const size_t bm = (size_t)blockIdx.x * 128, bn = (size_t)blockIdx.y * 128;

    frag_cd acc[4][4] = {};

    const int e = tid * 8;
    const int ar = e >> 5, ac = e & 31;
    const unsigned short* Ag  = A  + (bm + ar) * (size_t)K + ac;
    const unsigned short* Ag2 = Ag + (size_t)64 * K;
    const unsigned short* Bg  = Wt + (bn + ar) * (size_t)K + ac;
    const unsigned short* Bg2 = Bg + (size_t)64 * K;
    unsigned short* Asd = At + w * 512;
    unsigned short* Bsd = Bt + w * 512;

    for (int k0 = 0; k0 < K; k0 += 32) {
        __syncthreads();
        GLD16(Ag  + k0, Asd);
        GLD16(Ag2 + k0, Asd + 2048);
        GLD16(Bg  + k0, Bsd);
        GLD16(Bg2 + k0, Bsd + 2048);
        __syncthreads();
        frag_ab a[4], b[4];
#pragma unroll
        for (int i = 0; i < 4; ++i)
            a[i] = *(const frag_ab*)&At[(wm + i * 16 + lr) * 32 + quad * 8];
#pragma unroll
        for (int j = 0; j < 4; ++j)
            b[j] = *(const frag_ab*)&Bt[(wn + j * 16 + lr) * 32 + quad * 8];
#pragma unroll
        for (int i = 0; i < 4; ++i)
#pragma unroll
            for (int j = 0; j < 4; ++j)
                acc[i][j] = __builtin_amdgcn_mfma_f32_16x16x32_bf16(a[i], b[j], acc[i][j], 0, 0, 0);
    }

#pragma unroll
    for (int j = 0; j < 4; ++j) {
        const int col = (int)bn + wn + j * 16 + lr;
        const float bv = bias[col];
#pragma unroll
        for (int i = 0; i < 4; ++i) {
            const int rowb = (int)bm + wm + i * 16 + quad * 4;
#pragma unroll
            for (int r = 0; r < 4; ++r) {
                float v = acc[i][j][r] + bv;
                if (relu) v = fmaxf(v, 0.f);
                outB[(size_t)(rowb + r) * N + col] = f2b(v);
            }
        }
    }
}

// ---------- residual GEMM: outB = A@W^T + bias + residual, 128x128 ------------
// resA/resB f32 (rows <8192 / >=8192). If resA==null: residual = b2f(outB[idx])
// (in-place). grid (M/128, N/128).
__global__ __launch_bounds__(256) void gemm_res(
    const unsigned short* __restrict__ A, const unsigned short* __restrict__ Wt,
    const float* __restrict__ bias,
    const float* __restrict__ resA, const float* __restrict__ resB,
    unsigned short* __restrict__ outB, int M, int N, int K)
{
    __shared__ __align__(16) unsigned short At[128 * 32];
    __shared__ __align__(16) unsigned short Bt[128 * 32];
    const int tid = threadIdx.x;
    const int lane = tid & 63;
    const int w = tid >> 6;
    const int wm = (w >> 1) * 64, wn = (w & 1) * 64;
    const int lr = lane & 15;
    const int quad = lane >> 4;
    const size_t bm = (size_t)blockIdx.x * 128, bn = (size_t)blockIdx.y * 128;

    frag_cd acc[4][4] = {};

    const int e = tid * 8;
    const int ar = e >> 5, ac = e & 31;
    const unsigned short* Ag  = A  + (bm + ar) * (size_t)K + ac;
    const unsigned short* Ag2 = Ag + (size_t)64 * K;
    const unsigned short* Bg  = Wt + (bn + ar) * (size_t)K + ac;
    const unsigned short* Bg2 = Bg + (size_t)64 * K;
    unsigned short* Asd = At + w * 512;
    unsigned short* Bsd = Bt + w * 512;

    for (int k0 = 0; k0 < K; k0 += 32) {
        __syncthreads();
        GLD16(Ag  + k0, Asd);
        GLD16(Ag2 + k0, Asd + 2048);
        GLD16(Bg  + k0, Bsd);
        GLD16(Bg2 + k0, Bsd + 2048);
        __syncthreads();
        frag_ab a[4], b[4];
#pragma unroll
        for (int i = 0; i < 4; ++i)
            a[i] = *(const frag_ab*)&At[(wm + i * 16 + lr) * 32 + quad * 8];
#pragma unroll
        for (int j = 0; j < 4; ++j)
            b[j] = *(const frag_ab*)&Bt[(wn + j * 16 + lr) * 32 + quad * 8];
#pragma unroll
        for (int i = 0; i < 4; ++i)
#pragma unroll
            for (int j = 0; j < 4; ++j)
                acc[i][j] = __builtin_amdgcn_mfma_f32_16x16x32_bf16(a[i], b[j], acc[i][j], 0, 0, 0);
    }

#pragma unroll
    for (int j = 0; j < 4; ++j) {
        const int col = (int)bn + wn + j * 16 + lr;
        const float bv = bias[col];
#pragma unroll
        for (int i = 0; i < 4; ++i) {
            const int rowb = (int)bm + wm + i * 16 + quad * 4;
#pragma unroll
            for (int r = 0; r < 4; ++r) {
                const int row = rowb + r;
                const size_t idx = (size_t)row * N + col;
                float v = acc[i][j][r] + bv;
                if (resA)
                    v += (row < 8192) ? resA[idx] : resB[idx - (size_t)8192 * N];
                else
                    v += b2f(outB[idx]);
                outB[idx] = f2b(v);
            }
        }
    }
}

// -------- merged fp32->bf16 converts + S zero + QKV bias concat --------
__global__ __launch_bounds__(256) void convert_all(
    const float* __restrict__ Wq, const float* __restrict__ Wk,
    const float* __restrict__ Wv, const float* __restrict__ Wo,
    const float* __restrict__ W1, const float* __restrict__ W2,
    const float* __restrict__ question, const float* __restrict__ query,
    const float* __restrict__ bqp, const float* __restrict__ bkp,
    const float* __restrict__ bvp,
    unsigned short* __restrict__ Wqkvb, unsigned short* __restrict__ Wob,
    unsigned short* __restrict__ W1b, unsigned short* __restrict__ W2b,
    unsigned short* __restrict__ Xb, float* __restrict__ S,
    float* __restrict__ bqkv)
{
    const int b = blockIdx.x;
    const float* src; unsigned short* dst; size_t off;
    if (b < 256)        { src = Wq; dst = Wqkvb;          off = (size_t)b * 1024; }
    else if (b < 512)   { src = Wk; dst = Wqkvb + 262144; off = (size_t)(b - 256) * 1024; }
    else if (b < 768)   { src = Wv; dst = Wqkvb + 524288; off = (size_t)(b - 512) * 1024; }
    else if (b < 1024)  { src = Wo; dst = Wob;            off = (size_t)(b - 768) * 1024; }
    else if (b < 2048)  { src = W1; dst = W1b;            off = (size_t)(b - 1024) * 1024; }
    else if (b < 3072)  { src = W2; dst = W2b;            off = (size_t)(b - 2048) * 1024; }
    else if (b < 7168)  { src = question; dst = Xb;       off = (size_t)(b - 3072) * 1024; }
    else if (b < 11264) { src = query; dst = Xb + 4194304; off = (size_t)(b - 7168) * 1024; }
    else if (b < 11392) {
        const size_t idx = ((size_t)(b - 11264) * 256 + threadIdx.x) * 4;
        *(float4*)(S + idx) = make_float4(0.f, 0.f, 0.f, 0.f);
        return;
    } else {
        const int n = (b - 11392) * 256 + threadIdx.x;
        bqkv[n] = (n < 512) ? bqp[n] : (n < 1024) ? bkp[n - 512] : bvp[n - 1024];
        return;
    }
    const size_t idx = off + threadIdx.x * 4;
    float4 v = *(const float4*)(src + idx);
    ushort4 o;
    o.x = f2b(v.x); o.y = f2b(v.y); o.z = f2b(v.z); o.w = f2b(v.w);
    *(ushort4*)(dst + idx) = o;
}

// ------- S[b,h] += sum over both halves of K^T outer V (merged QKV) -------
__global__ __launch_bounds__(256) void s_kernel(
    const unsigned short* __restrict__ QKV, float* __restrict__ S)
{
    const int bh = blockIdx.x, chunk = blockIdx.y;
    const int b = bh >> 3, h = bh & 7;
    __shared__ float Ks[8][64];
    __shared__ float Vs[8][64];
    const int tid = threadIdx.x;
    const int tx = tid & 15, ty = tid >> 4;
    float acc[4][4] = {};
    for (int pass = 0; pass < 2; ++pass) {
        for (int l0 = 0; l0 < 128; l0 += 8) {
#pragma unroll
            for (int it = 0; it < 2; ++it) {
                const int e = tid + it * 256;
                const int rr = e >> 6, cc = e & 63;
                const size_t row = (size_t)pass * 8192 + (size_t)b * Lq + chunk * 128 + l0 + rr;
                Ks[rr][cc] = b2f(QKV[row * 1536 + 512 + h * 64 + cc]);
                Vs[rr][cc] = b2f(QKV[row * 1536 + 1024 + h * 64 + cc]);
            }
            __syncthreads();
#pragma unroll
            for (int rr = 0; rr < 8; ++rr) {
                float kv[4], vv[4];
#pragma unroll
                for (int i = 0; i < 4; ++i) kv[i] = Ks[rr][ty * 4 + i];
#pragma unroll
                for (int j = 0; j < 4; ++j) vv[j] = Vs[rr][tx * 4 + j];
#pragma unroll
                for (int i = 0; i < 4; ++i)
#pragma unroll
                    for (int j = 0; j < 4; ++j)
                        acc[i][j] = fmaf(kv[i], vv[j], acc[i][j]);
            }
            __syncthreads();
        }
    }
#pragma unroll
    for (int i = 0; i < 4; ++i)
#pragma unroll
        for (int j = 0; j < 4; ++j)
            atomicAdd(&S[((size_t)bh * 64 + ty * 4 + i) * 64 + tx * 4 + j], acc[i][j]);
}

// ------- S fp32 -> Sbt bf16, B-operand layout [bh][khalf][n][kj] -------
__global__ __launch_bounds__(256) void sbt_convert(
    const float* __restrict__ S, unsigned short* __restrict__ Sbt)
{
    const int bh = blockIdx.x;
    const float* Sp = S + (size_t)bh * 4096;
    unsigned short* Dp = Sbt + (size_t)bh * 4096;
    const int t = threadIdx.x;
#pragma unroll
    for (int u = 0; u < 16; ++u) {
        const int d = t * 16 + u;
        const int kj = d & 31, n = (d >> 5) & 63, kk = d >> 11;
        Dp[d] = f2b(Sp[(size_t)(kk * 32 + kj) * 64 + n]);
    }
}

// ------- attn = Q @ S_bh via MFMA; block: 128 rows x 64 cols (one head) -------
__global__ __launch_bounds__(256) void attn_mfma(
    const unsigned short* __restrict__ QKV, const unsigned short* __restrict__ Sbt,
    unsigned short* __restrict__ Ob)
{
    __shared__ __align__(16) unsigned short At[2 * 128 * 32];
    __shared__ __align__(16) unsigned short Bt[2 * 64 * 32];
    const int h = blockIdx.x;
    const int rbase = blockIdx.y * 128;
    const int b = (rbase >> 11) & 3;
    const int bh = b * 8 + h;
    const int tid = threadIdx.x;
    const int lane = tid & 63;
    const int w = tid >> 6;
    const int lr = lane & 15;
    const int quad = lane >> 4;

    {
        const int rloc = tid >> 2, c8 = (tid & 3) * 8;
#pragma unroll
        for (int it = 0; it < 4; ++it) {
            const int kk = it & 1, rh = it >> 1;
            const unsigned short* g = QKV +
                ((size_t)rbase + rh * 64 + rloc) * 1536 + h * 64 + kk * 32 + c8;
            GLD16(g, At + kk * 4096 + rh * 2048 + w * 512);
        }
        const unsigned short* Sg = Sbt + (size_t)bh * 4096 + tid * 8;
#pragma unroll
        for (int bi = 0; bi < 2; ++bi)
            GLD16(Sg + bi * 2048, Bt + bi * 2048 + w * 512);
    }
    __syncthreads();

    frag_cd acc[2][4] = {};
#pragma unroll
    for (int kk = 0; kk < 2; ++kk) {
        frag_ab a[2], bfr[4];
#pragma unroll
        for (int i = 0; i < 2; ++i)
            a[i] = *(const frag_ab*)&At[kk * 4096 + (w * 32 + i * 16 + lr) * 32 + quad * 8];
#pragma unroll
        for (int j = 0; j < 4; ++j)
            bfr[j] = *(const frag_ab*)&Bt[kk * 2048 + (j * 16 + lr) * 32 + quad * 8];
#pragma unroll
        for (int i = 0; i < 2; ++i)
#pragma unroll
            for (int j = 0; j < 4; ++j)
                acc[i][j] = __builtin_amdgcn_mfma_f32_16x16x32_bf16(a[i], bfr[j], acc[i][j], 0, 0, 0);
    }

#pragma unroll
    for (int i = 0; i < 2; ++i) {
        const int rowb = rbase + w * 32 + i * 16 + quad * 4;
#pragma unroll
        for (int j = 0; j < 4; ++j) {
            const int col = h * 64 + j * 16 + lr;
#pragma unroll
            for (int r = 0; r < 4; ++r)
                Ob[(size_t)(rowb + r) * 512 + col] = f2b(acc[i][j][r]);
        }
    }
}

// ------- LN over bf16 row (512) in place -------
__global__ __launch_bounds__(256) void ln_b16_inplace(
    unsigned short* __restrict__ Y, const float* __restrict__ g,
    const float* __restrict__ bta)
{
    __shared__ float red[256];
    const int row = blockIdx.x;
    const int t = threadIdx.x;
    unsigned short* yr = Y + (size_t)row * Dq;
    float v0 = b2f(yr[t]), v1 = b2f(yr[t + 256]);
    red[t] = v0 + v1;
    __syncthreads();
    for (int s = 128; s > 0; s >>= 1) { if (t < s) red[t] += red[t + s]; __syncthreads(); }
    const float mean = red[0] * (1.f / Dq);
    __syncthreads();
    const float d0 = v0 - mean, d1 = v1 - mean;
    red[t] = d0 * d0 + d1 * d1;
    __syncthreads();
    for (int s = 128; s > 0; s >>= 1) { if (t < s) red[t] += red[t + s]; __syncthreads(); }
    const float rstd = rsqrtf(red[0] * (1.f / Dq) + 1e-5f);
    yr[t] = f2b(d0 * rstd * g[t] + bta[t]);
    yr[t + 256] = f2b(d1 * rstd * g[t + 256] + bta[t + 256]);
}

// ------- LN over bf16 row -> out f32 half-columns (merged rows) -------
__global__ __launch_bounds__(256) void ln_b16_out(
    const unsigned short* __restrict__ Y, const float* __restrict__ g,
    const float* __restrict__ bta, float* __restrict__ out)
{
    __shared__ float red[256];
    const int row = blockIdx.x;
    const int t = threadIdx.x;
    const unsigned short* yr = Y + (size_t)row * Dq;
    float v0 = b2f(yr[t]), v1 = b2f(yr[t + 256]);
    red[t] = v0 + v1;
    __syncthreads();
    for (int s = 128; s > 0; s >>= 1) { if (t < s) red[t] += red[t + s]; __syncthreads(); }
    const float mean = red[0] * (1.f / Dq);
    __syncthreads();
    const float d0 = v0 - mean, d1 = v1 - mean;
    red[t] = d0 * d0 + d1 * d1;
    __syncthreads();
    for (int s = 128; s > 0; s >>= 1) { if (t < s) red[t] += red[t + s]; __syncthreads(); }
    const float rstd = rsqrtf(red[0] * (1.f / Dq) + 1e-5f);
    const int half = row >> 13, br = row & 8191;
    float* orow = out + (size_t)br * 1024 + half * 512;
    orow[t] = d0 * rstd * g[t] + bta[t];
    orow[t + 256] = d1 * rstd * g[t + 256] + bta[t + 256];
}

extern "C" void kernel_launch(void* const* d_in, const int* in_sizes, int n_in,
                              void* d_out, int out_size, void* d_ws, size_t ws_size,
                              hipStream_t stream)
{
    const float* question = (const float*)d_in[0];
    const float* query    = (const float*)d_in[1];
    const float* Wq = (const float*)d_in[2];  const float* bqp = (const float*)d_in[3];
    const float* Wk = (const float*)d_in[4];  const float* bkp = (const float*)d_in[5];
    const float* Wv = (const float*)d_in[6];  const float* bvp = (const float*)d_in[7];
    const float* Wo = (const float*)d_in[8];  const float* bo  = (const float*)d_in[9];
    const float* ln_g = (const float*)d_in[10]; const float* ln_b = (const float*)d_in[11];
    const float* W1 = (const float*)d_in[12]; const float* b1 = (const float*)d_in[13];
    const float* W2 = (const float*)d_in[14]; const float* b2 = (const float*)d_in[15];
    float* out = (float*)d_out;
    char* ws = (char*)d_ws;

    // ---- workspace (~87 MiB) ----
    // R0 [0,48M): QKVb bf16 [16384,1536]      -> h[0:48M) later
    // R1 [48,64M): attnb bf16 [16384,512]     -> h[48:64M) later
    // R2 [64,80M): Xb bf16 in -> y0b/xb/y bf16 (LN1 in-place; FFN2 in-place)
    // [80M,80.5M): S f32; then weights bf16 + Sbt + bqkv
    unsigned short* QKVb  = (unsigned short*)(ws);
    unsigned short* attnb = (unsigned short*)(ws + 48 * MiBu);
    unsigned short* Xb    = (unsigned short*)(ws + 64 * MiBu);
    unsigned short* xbuf  = (unsigned short*)(ws + 64 * MiBu);  // y0b -> xb -> y
    unsigned short* hb    = (unsigned short*)(ws);              // [16384,2048] bf16
    float* S = (float*)(ws + 80 * MiBu);
    char* wp = ws + 80 * MiBu + 524288;
    unsigned short* Wqkvb = (unsigned short*)wp;  wp += 1536 * 512 * 2;
    unsigned short* Wob   = (unsigned short*)wp;  wp += 512 * 512 * 2;
    unsigned short* W1b   = (unsigned short*)wp;  wp += 2048 * 512 * 2;
    unsigned short* W2b   = (unsigned short*)wp;  wp += 512 * 2048 * 2;
    unsigned short* Sbt   = (unsigned short*)wp;  wp += 32 * 4096 * 2;
    float* bqkv           = (float*)wp;

    dim3 blk(256);

    convert_all<<<11398, blk, 0, stream>>>(Wq, Wk, Wv, Wo, W1, W2, question, query,
                                           bqp, bkp, bvp,
                                           Wqkvb, Wob, W1b, W2b, Xb, S, bqkv);

    // QKV: [16384,512]@[1536,512]^T -> bf16; M-major grid (1536 blocks, 6/CU)
    gemm_bf16<<<dim3(128, 12), blk, 0, stream>>>(Xb, Wqkvb, bqkv, QKVb,
                                                 Mrows, 1536, 512, 0);

    // S accumulation (fp32) -> bf16 B-layout; attn via MFMA (1024 blocks)
    s_kernel<<<dim3(32, 16), blk, 0, stream>>>(QKVb, S);
    sbt_convert<<<32, blk, 0, stream>>>(S, Sbt);
    attn_mfma<<<dim3(8, 128), blk, 0, stream>>>(QKVb, Sbt, attnb);

    // o-proj + residual(inputs) + bo -> bf16 y0b (512 blocks)
    gemm_res<<<dim3(128, 4), blk, 0, stream>>>(attnb, Wob, bo, question, query,
                                               xbuf, Mrows, 512, 512);

    // LN1 in place: xb = LN(y0b)
    ln_b16_inplace<<<Mrows, blk, 0, stream>>>(xbuf, ln_g, ln_b);

    // FFN1 full-M: h = relu(xb @ W1^T + b1) -> bf16 [16384,2048] (2048 blocks)
    gemm_bf16<<<dim3(128, 16), blk, 0, stream>>>(xbuf, W1b, b1, hb,
                                                 Mrows, PFq, 512, 1);

    // FFN2 full-M, K=2048: y = h @ W2^T + b2 + xb, bf16 in place (512 blocks)
    gemm_res<<<dim3(128, 4), blk, 0, stream>>>(hb, W2b, b2, nullptr, nullptr,
                                               xbuf, Mrows, 512, PFq);

    // LN2 -> out halves
    ln_b16_out<<<Mrows, blk, 0, stream>>>(xbuf, ln_g, ln_b, out);
}

// Round 7
// 396.022 us; speedup vs baseline: 1.2156x; 1.0349x over previous
//
#include <hip/hip_runtime.h>
#include <stdint.h>

// CrossAttention via linear-attention algebra, both halves merged to M=16384:
//   S = K1^T V1 + K2^T V2 (per b,h; 64x64), shared by both halves.
//   attn = Q @ S ; x = LN(inp + attn@Wo^T + bo) ; out = LN(x + FF(x))
// bf16 MFMA GEMMs. Wide-M GEMMs (QKV, FFN1): 128x128 tiles. Narrow-N GEMMs
// (o-proj, FFN2): 128x64 tiles -> 1024 blocks = 4/CU (R6: 128x128 at N=512
// gave only 2 blocks/CU and 466 TF; blocks/CU is what feeds the structure).
// M-major grids keep a row-band's N-tiles on one XCD. Fused epilogues.

#define Bq 4
#define Lq 2048
#define Dq 512
#define PFq 2048
#define Mrows 16384
#define MiBu 1048576ull

typedef __attribute__((ext_vector_type(8))) short frag_ab;
typedef __attribute__((ext_vector_type(4))) float frag_cd;

__device__ __forceinline__ unsigned short f2b(float f) {
    union { float f; uint32_t u; } x; x.f = f;
    uint32_t r = x.u + 0x7fffu + ((x.u >> 16) & 1u);
    return (unsigned short)(r >> 16);
}
__device__ __forceinline__ float b2f(unsigned short u) {
    union { uint32_t u; float f; } x; x.u = ((uint32_t)u) << 16;
    return x.f;
}

#define GLD16(g, l)                                                              \
    __builtin_amdgcn_global_load_lds(                                            \
        (const __attribute__((address_space(1))) void*)(const void*)(g),         \
        (__attribute__((address_space(3))) void*)(void*)(l), 16, 0, 0)

// ---------- bf16 MFMA GEMM: outB = A[M,K]b @ W[N,K]b^T + bias (+relu) ----------
// 128x128 tile; grid (M/128, N/128), block 256
__global__ __launch_bounds__(256) void gemm_bf16(
    const unsigned short* __restrict__ A, const unsigned short* __restrict__ Wt,
    const float* __restrict__ bias, unsigned short* __restrict__ outB,
    int M, int N, int K, int relu)
{
    __shared__ __align__(16) unsigned short At[128 * 32];
    __shared__ __align__(16) unsigned short Bt[128 * 32];
    const int tid = threadIdx.x;
    const int lane = tid & 63;
    const int w = tid >> 6;
    const int wm = (w >> 1) * 64, wn = (w & 1) * 64;
    const int lr = lane & 15;
    const int quad = lane >> 4;
    const size_t bm = (size_t)blockIdx.x * 128, bn = (size_t)blockIdx.y * 128;

    frag_cd acc[4][4] = {};

    const int e = tid * 8;
    const int ar = e >> 5, ac = e & 31;
    const unsigned short* Ag  = A  + (bm + ar) * (size_t)K + ac;
    const unsigned short* Ag2 = Ag + (size_t)64 * K;
    const unsigned short* Bg  = Wt + (bn + ar) * (size_t)K + ac;
    const unsigned short* Bg2 = Bg + (size_t)64 * K;
    unsigned short* Asd = At + w * 512;
    unsigned short* Bsd = Bt + w * 512;

    for (int k0 = 0; k0 < K; k0 += 32) {
        __syncthreads();
        GLD16(Ag  + k0, Asd);
        GLD16(Ag2 + k0, Asd + 2048);
        GLD16(Bg  + k0, Bsd);
        GLD16(Bg2 + k0, Bsd + 2048);
        __syncthreads();
        frag_ab a[4], b[4];
#pragma unroll
        for (int i = 0; i < 4; ++i)
            a[i] = *(const frag_ab*)&At[(wm + i * 16 + lr) * 32 + quad * 8];
#pragma unroll
        for (int j = 0; j < 4; ++j)
            b[j] = *(const frag_ab*)&Bt[(wn + j * 16 + lr) * 32 + quad * 8];
#pragma unroll
        for (int i = 0; i < 4; ++i)
#pragma unroll
            for (int j = 0; j < 4; ++j)
                acc[i][j] = __builtin_amdgcn_mfma_f32_16x16x32_bf16(a[i], b[j], acc[i][j], 0, 0, 0);
    }

#pragma unroll
    for (int j = 0; j < 4; ++j) {
        const int col = (int)bn + wn + j * 16 + lr;
        const float bv = bias[col];
#pragma unroll
        for (int i = 0; i < 4; ++i) {
            const int rowb = (int)bm + wm + i * 16 + quad * 4;
#pragma unroll
            for (int r = 0; r < 4; ++r) {
                float v = acc[i][j][r] + bv;
                if (relu) v = fmaxf(v, 0.f);
                outB[(size_t)(rowb + r) * N + col] = f2b(v);
            }
        }
    }
}

// ---------- narrow-N residual GEMM: 128x64 tile, 4+ blocks/CU ------------------
// outB = A@W^T + bias + residual. resA/resB f32 (rows <8192 / >=8192).
// resA==null: residual = b2f(outB[idx]) (in-place). grid (M/128, N/64).
__global__ __launch_bounds__(256) void gemm_res(
    const unsigned short* __restrict__ A, const unsigned short* __restrict__ Wt,
    const float* __restrict__ bias,
    const float* __restrict__ resA, const float* __restrict__ resB,
    unsigned short* __restrict__ outB, int M, int N, int K)
{
    __shared__ __align__(16) unsigned short At[128 * 32];
    __shared__ __align__(16) unsigned short Bt[64 * 32];
    const int tid = threadIdx.x;
    const int lane = tid & 63;
    const int w = tid >> 6;
    const int wm = w * 32;                 // wave rows within 128-tile
    const int lr = lane & 15;
    const int quad = lane >> 4;
    const size_t bm = (size_t)blockIdx.x * 128, bn = (size_t)blockIdx.y * 64;

    frag_cd acc[2][4] = {};

    const int e = tid * 8;
    const int ar = e >> 5, ac = e & 31;    // 64 rows x 32 cols per issue
    const unsigned short* Ag  = A  + (bm + ar) * (size_t)K + ac;
    const unsigned short* Ag2 = Ag + (size_t)64 * K;
    const unsigned short* Bg  = Wt + (bn + ar) * (size_t)K + ac;
    unsigned short* Asd = At + w * 512;
    unsigned short* Bsd = Bt + w * 512;

    for (int k0 = 0; k0 < K; k0 += 32) {
        __syncthreads();
        GLD16(Ag  + k0, Asd);
        GLD16(Ag2 + k0, Asd + 2048);
        GLD16(Bg  + k0, Bsd);
        __syncthreads();
        frag_ab a[2], b[4];
#pragma unroll
        for (int i = 0; i < 2; ++i)
            a[i] = *(const frag_ab*)&At[(wm + i * 16 + lr) * 32 + quad * 8];
#pragma unroll
        for (int j = 0; j < 4; ++j)
            b[j] = *(const frag_ab*)&Bt[(j * 16 + lr) * 32 + quad * 8];
#pragma unroll
        for (int i = 0; i < 2; ++i)
#pragma unroll
            for (int j = 0; j < 4; ++j)
                acc[i][j] = __builtin_amdgcn_mfma_f32_16x16x32_bf16(a[i], b[j], acc[i][j], 0, 0, 0);
    }

#pragma unroll
    for (int j = 0; j < 4; ++j) {
        const int col = (int)bn + j * 16 + lr;
        const float bv = bias[col];
#pragma unroll
        for (int i = 0; i < 2; ++i) {
            const int rowb = (int)bm + wm + i * 16 + quad * 4;
#pragma unroll
            for (int r = 0; r < 4; ++r) {
                const int row = rowb + r;
                const size_t idx = (size_t)row * N + col;
                float v = acc[i][j][r] + bv;
                if (resA)
                    v += (row < 8192) ? resA[idx] : resB[idx - (size_t)8192 * N];
                else
                    v += b2f(outB[idx]);
                outB[idx] = f2b(v);
            }
        }
    }
}

// -------- merged fp32->bf16 converts + S zero + QKV bias concat --------
__global__ __launch_bounds__(256) void convert_all(
    const float* __restrict__ Wq, const float* __restrict__ Wk,
    const float* __restrict__ Wv, const float* __restrict__ Wo,
    const float* __restrict__ W1, const float* __restrict__ W2,
    const float* __restrict__ question, const float* __restrict__ query,
    const float* __restrict__ bqp, const float* __restrict__ bkp,
    const float* __restrict__ bvp,
    unsigned short* __restrict__ Wqkvb, unsigned short* __restrict__ Wob,
    unsigned short* __restrict__ W1b, unsigned short* __restrict__ W2b,
    unsigned short* __restrict__ Xb, float* __restrict__ S,
    float* __restrict__ bqkv)
{
    const int b = blockIdx.x;
    const float* src; unsigned short* dst; size_t off;
    if (b < 256)        { src = Wq; dst = Wqkvb;          off = (size_t)b * 1024; }
    else if (b < 512)   { src = Wk; dst = Wqkvb + 262144; off = (size_t)(b - 256) * 1024; }
    else if (b < 768)   { src = Wv; dst = Wqkvb + 524288; off = (size_t)(b - 512) * 1024; }
    else if (b < 1024)  { src = Wo; dst = Wob;            off = (size_t)(b - 768) * 1024; }
    else if (b < 2048)  { src = W1; dst = W1b;            off = (size_t)(b - 1024) * 1024; }
    else if (b < 3072)  { src = W2; dst = W2b;            off = (size_t)(b - 2048) * 1024; }
    else if (b < 7168)  { src = question; dst = Xb;       off = (size_t)(b - 3072) * 1024; }
    else if (b < 11264) { src = query; dst = Xb + 4194304; off = (size_t)(b - 7168) * 1024; }
    else if (b < 11392) {
        const size_t idx = ((size_t)(b - 11264) * 256 + threadIdx.x) * 4;
        *(float4*)(S + idx) = make_float4(0.f, 0.f, 0.f, 0.f);
        return;
    } else {
        const int n = (b - 11392) * 256 + threadIdx.x;
        bqkv[n] = (n < 512) ? bqp[n] : (n < 1024) ? bkp[n - 512] : bvp[n - 1024];
        return;
    }
    const size_t idx = off + threadIdx.x * 4;
    float4 v = *(const float4*)(src + idx);
    ushort4 o;
    o.x = f2b(v.x); o.y = f2b(v.y); o.z = f2b(v.z); o.w = f2b(v.w);
    *(ushort4*)(dst + idx) = o;
}

// ------- S[b,h] += sum over both halves of K^T outer V (merged QKV) -------
__global__ __launch_bounds__(256) void s_kernel(
    const unsigned short* __restrict__ QKV, float* __restrict__ S)
{
    const int bh = blockIdx.x, chunk = blockIdx.y;
    const int b = bh >> 3, h = bh & 7;
    __shared__ float Ks[8][64];
    __shared__ float Vs[8][64];
    const int tid = threadIdx.x;
    const int tx = tid & 15, ty = tid >> 4;
    float acc[4][4] = {};
    for (int pass = 0; pass < 2; ++pass) {
        for (int l0 = 0; l0 < 128; l0 += 8) {
#pragma unroll
            for (int it = 0; it < 2; ++it) {
                const int e = tid + it * 256;
                const int rr = e >> 6, cc = e & 63;
                const size_t row = (size_t)pass * 8192 + (size_t)b * Lq + chunk * 128 + l0 + rr;
                Ks[rr][cc] = b2f(QKV[row * 1536 + 512 + h * 64 + cc]);
                Vs[rr][cc] = b2f(QKV[row * 1536 + 1024 + h * 64 + cc]);
            }
            __syncthreads();
#pragma unroll
            for (int rr = 0; rr < 8; ++rr) {
                float kv[4], vv[4];
#pragma unroll
                for (int i = 0; i < 4; ++i) kv[i] = Ks[rr][ty * 4 + i];
#pragma unroll
                for (int j = 0; j < 4; ++j) vv[j] = Vs[rr][tx * 4 + j];
#pragma unroll
                for (int i = 0; i < 4; ++i)
#pragma unroll
                    for (int j = 0; j < 4; ++j)
                        acc[i][j] = fmaf(kv[i], vv[j], acc[i][j]);
            }
            __syncthreads();
        }
    }
#pragma unroll
    for (int i = 0; i < 4; ++i)
#pragma unroll
        for (int j = 0; j < 4; ++j)
            atomicAdd(&S[((size_t)bh * 64 + ty * 4 + i) * 64 + tx * 4 + j], acc[i][j]);
}

// ------- S fp32 -> Sbt bf16, B-operand layout [bh][khalf][n][kj] -------
__global__ __launch_bounds__(256) void sbt_convert(
    const float* __restrict__ S, unsigned short* __restrict__ Sbt)
{
    const int bh = blockIdx.x;
    const float* Sp = S + (size_t)bh * 4096;
    unsigned short* Dp = Sbt + (size_t)bh * 4096;
    const int t = threadIdx.x;
#pragma unroll
    for (int u = 0; u < 16; ++u) {
        const int d = t * 16 + u;
        const int kj = d & 31, n = (d >> 5) & 63, kk = d >> 11;
        Dp[d] = f2b(Sp[(size_t)(kk * 32 + kj) * 64 + n]);
    }
}

// ------- attn = Q @ S_bh via MFMA; block: 128 rows x 64 cols (one head) -------
__global__ __launch_bounds__(256) void attn_mfma(
    const unsigned short* __restrict__ QKV, const unsigned short* __restrict__ Sbt,
    unsigned short* __restrict__ Ob)
{
    __shared__ __align__(16) unsigned short At[2 * 128 * 32];
    __shared__ __align__(16) unsigned short Bt[2 * 64 * 32];
    const int h = blockIdx.x;
    const int rbase = blockIdx.y * 128;
    const int b = (rbase >> 11) & 3;
    const int bh = b * 8 + h;
    const int tid = threadIdx.x;
    const int lane = tid & 63;
    const int w = tid >> 6;
    const int lr = lane & 15;
    const int quad = lane >> 4;

    {
        const int rloc = tid >> 2, c8 = (tid & 3) * 8;
#pragma unroll
        for (int it = 0; it < 4; ++it) {
            const int kk = it & 1, rh = it >> 1;
            const unsigned short* g = QKV +
                ((size_t)rbase + rh * 64 + rloc) * 1536 + h * 64 + kk * 32 + c8;
            GLD16(g, At + kk * 4096 + rh * 2048 + w * 512);
        }
        const unsigned short* Sg = Sbt + (size_t)bh * 4096 + tid * 8;
#pragma unroll
        for (int bi = 0; bi < 2; ++bi)
            GLD16(Sg + bi * 2048, Bt + bi * 2048 + w * 512);
    }
    __syncthreads();

    frag_cd acc[2][4] = {};
#pragma unroll
    for (int kk = 0; kk < 2; ++kk) {
        frag_ab a[2], bfr[4];
#pragma unroll
        for (int i = 0; i < 2; ++i)
            a[i] = *(const frag_ab*)&At[kk * 4096 + (w * 32 + i * 16 + lr) * 32 + quad * 8];
#pragma unroll
        for (int j = 0; j < 4; ++j)
            bfr[j] = *(const frag_ab*)&Bt[kk * 2048 + (j * 16 + lr) * 32 + quad * 8];
#pragma unroll
        for (int i = 0; i < 2; ++i)
#pragma unroll
            for (int j = 0; j < 4; ++j)
                acc[i][j] = __builtin_amdgcn_mfma_f32_16x16x32_bf16(a[i], bfr[j], acc[i][j], 0, 0, 0);
    }

#pragma unroll
    for (int i = 0; i < 2; ++i) {
        const int rowb = rbase + w * 32 + i * 16 + quad * 4;
#pragma unroll
        for (int j = 0; j < 4; ++j) {
            const int col = h * 64 + j * 16 + lr;
#pragma unroll
            for (int r = 0; r < 4; ++r)
                Ob[(size_t)(rowb + r) * 512 + col] = f2b(acc[i][j][r]);
        }
    }
}

// ------- LN over bf16 row (512) in place; wave-shuffle reduction -------
__global__ __launch_bounds__(256) void ln_b16_inplace(
    unsigned short* __restrict__ Y, const float* __restrict__ g,
    const float* __restrict__ bta)
{
    __shared__ float part[8];
    const int row = blockIdx.x;
    const int t = threadIdx.x;
    const int w = t >> 6;
    unsigned short* yr = Y + (size_t)row * Dq;
    const float v0 = b2f(yr[t]), v1 = b2f(yr[t + 256]);
    float s = v0 + v1;
#pragma unroll
    for (int off = 32; off; off >>= 1) s += __shfl_xor(s, off, 64);
    if ((t & 63) == 0) part[w] = s;
    __syncthreads();
    const float mean = (part[0] + part[1] + part[2] + part[3]) * (1.f / Dq);
    const float d0 = v0 - mean, d1 = v1 - mean;
    float q = d0 * d0 + d1 * d1;
#pragma unroll
    for (int off = 32; off; off >>= 1) q += __shfl_xor(q, off, 64);
    if ((t & 63) == 0) part[4 + w] = q;
    __syncthreads();
    const float rstd = rsqrtf((part[4] + part[5] + part[6] + part[7]) * (1.f / Dq) + 1e-5f);
    yr[t] = f2b(d0 * rstd * g[t] + bta[t]);
    yr[t + 256] = f2b(d1 * rstd * g[t + 256] + bta[t + 256]);
}

// ------- LN over bf16 row -> out f32 half-columns (merged rows) -------
__global__ __launch_bounds__(256) void ln_b16_out(
    const unsigned short* __restrict__ Y, const float* __restrict__ g,
    const float* __restrict__ bta, float* __restrict__ out)
{
    __shared__ float part[8];
    const int row = blockIdx.x;
    const int t = threadIdx.x;
    const int w = t >> 6;
    const unsigned short* yr = Y + (size_t)row * Dq;
    const float v0 = b2f(yr[t]), v1 = b2f(yr[t + 256]);
    float s = v0 + v1;
#pragma unroll
    for (int off = 32; off; off >>= 1) s += __shfl_xor(s, off, 64);
    if ((t & 63) == 0) part[w] = s;
    __syncthreads();
    const float mean = (part[0] + part[1] + part[2] + part[3]) * (1.f / Dq);
    const float d0 = v0 - mean, d1 = v1 - mean;
    float q = d0 * d0 + d1 * d1;
#pragma unroll
    for (int off = 32; off; off >>= 1) q += __shfl_xor(q, off, 64);
    if ((t & 63) == 0) part[4 + w] = q;
    __syncthreads();
    const float rstd = rsqrtf((part[4] + part[5] + part[6] + part[7]) * (1.f / Dq) + 1e-5f);
    const int half = row >> 13, br = row & 8191;
    float* orow = out + (size_t)br * 1024 + half * 512;
    orow[t] = d0 * rstd * g[t] + bta[t];
    orow[t + 256] = d1 * rstd * g[t + 256] + bta[t + 256];
}

extern "C" void kernel_launch(void* const* d_in, const int* in_sizes, int n_in,
                              void* d_out, int out_size, void* d_ws, size_t ws_size,
                              hipStream_t stream)
{
    const float* question = (const float*)d_in[0];
    const float* query    = (const float*)d_in[1];
    const float* Wq = (const float*)d_in[2];  const float* bqp = (const float*)d_in[3];
    const float* Wk = (const float*)d_in[4];  const float* bkp = (const float*)d_in[5];
    const float* Wv = (const float*)d_in[6];  const float* bvp = (const float*)d_in[7];
    const float* Wo = (const float*)d_in[8];  const float* bo  = (const float*)d_in[9];
    const float* ln_g = (const float*)d_in[10]; const float* ln_b = (const float*)d_in[11];
    const float* W1 = (const float*)d_in[12]; const float* b1 = (const float*)d_in[13];
    const float* W2 = (const float*)d_in[14]; const float* b2 = (const float*)d_in[15];
    float* out = (float*)d_out;
    char* ws = (char*)d_ws;

    // ---- workspace (~87 MiB) ----
    // R0 [0,48M): QKVb bf16 [16384,1536]      -> h[0:48M) later
    // R1 [48,64M): attnb bf16 [16384,512]     -> h[48:64M) later
    // R2 [64,80M): Xb bf16 in -> y0b/xb/y bf16 (LN1 in-place; FFN2 in-place)
    // [80M,80.5M): S f32; then weights bf16 + Sbt + bqkv
    unsigned short* QKVb  = (unsigned short*)(ws);
    unsigned short* attnb = (unsigned short*)(ws + 48 * MiBu);
    unsigned short* Xb    = (unsigned short*)(ws + 64 * MiBu);
    unsigned short* xbuf  = (unsigned short*)(ws + 64 * MiBu);  // y0b -> xb -> y
    unsigned short* hb    = (unsigned short*)(ws);              // [16384,2048] bf16
    float* S = (float*)(ws + 80 * MiBu);
    char* wp = ws + 80 * MiBu + 524288;
    unsigned short* Wqkvb = (unsigned short*)wp;  wp += 1536 * 512 * 2;
    unsigned short* Wob   = (unsigned short*)wp;  wp += 512 * 512 * 2;
    unsigned short* W1b   = (unsigned short*)wp;  wp += 2048 * 512 * 2;
    unsigned short* W2b   = (unsigned short*)wp;  wp += 512 * 2048 * 2;
    unsigned short* Sbt   = (unsigned short*)wp;  wp += 32 * 4096 * 2;
    float* bqkv           = (float*)wp;

    dim3 blk(256);

    convert_all<<<11398, blk, 0, stream>>>(Wq, Wk, Wv, Wo, W1, W2, question, query,
                                           bqp, bkp, bvp,
                                           Wqkvb, Wob, W1b, W2b, Xb, S, bqkv);

    // QKV: [16384,512]@[1536,512]^T -> bf16; M-major grid (1536 blocks, 6/CU)
    gemm_bf16<<<dim3(128, 12), blk, 0, stream>>>(Xb, Wqkvb, bqkv, QKVb,
                                                 Mrows, 1536, 512, 0);

    // S accumulation (fp32) -> bf16 B-layout; attn via MFMA (1024 blocks)
    s_kernel<<<dim3(32, 16), blk, 0, stream>>>(QKVb, S);
    sbt_convert<<<32, blk, 0, stream>>>(S, Sbt);
    attn_mfma<<<dim3(8, 128), blk, 0, stream>>>(QKVb, Sbt, attnb);

    // o-proj + residual(inputs) + bo -> bf16 y0b (128x64 tiles, 1024 blocks)
    gemm_res<<<dim3(128, 8), blk, 0, stream>>>(attnb, Wob, bo, question, query,
                                               xbuf, Mrows, 512, 512);

    // LN1 in place: xb = LN(y0b)
    ln_b16_inplace<<<Mrows, blk, 0, stream>>>(xbuf, ln_g, ln_b);

    // FFN1 full-M: h = relu(xb @ W1^T + b1) -> bf16 [16384,2048] (2048 blocks)
    gemm_bf16<<<dim3(128, 16), blk, 0, stream>>>(xbuf, W1b, b1, hb,
                                                 Mrows, PFq, 512, 1);

    // FFN2 full-M, K=2048: y = h @ W2^T + b2 + xb, bf16 in place
    // (128x64 tiles, 1024 blocks, 4/CU)
    gemm_res<<<dim3(128, 8), blk, 0, stream>>>(hb, W2b, b2, nullptr, nullptr,
                                               xbuf, Mrows, 512, PFq);

    // LN2 -> out halves
    ln_b16_out<<<Mrows, blk, 0, stream>>>(xbuf, ln_g, ln_b, out);
}

// Round 8
// 390.624 us; speedup vs baseline: 1.2324x; 1.0138x over previous
//
#include <hip/hip_runtime.h>
#include <stdint.h>

// CrossAttention via linear-attention algebra, both halves merged to M=16384:
//   S = K1^T V1 + K2^T V2 (per b,h; 64x64), shared by both halves.
//   attn = Q @ S ; x = LN(inp + attn@Wo^T + bo) ; out = LN(x + FF(x))
// bf16 MFMA GEMMs, BK=64, XOR-swizzled LDS (R7: stride-32 rows gave 8-way
// bank conflicts, 4-6M SQ_LDS_BANK_CONFLICT -> LDS-read-bound at 20% MfmaUtil).
// Swizzle: LDS[row][slot] holds global chunk (slot ^ (row&7)); frag read of
// chunk c uses slot c ^ (lr&7) -> 2-way max (free). M-major grids; fused
// epilogues (o-proj += inp+bo; FFN2 += b2+x in place).

#define Bq 4
#define Lq 2048
#define Dq 512
#define PFq 2048
#define Mrows 16384
#define MiBu 1048576ull

typedef __attribute__((ext_vector_type(8))) short frag_ab;
typedef __attribute__((ext_vector_type(4))) float frag_cd;

__device__ __forceinline__ unsigned short f2b(float f) {
    union { float f; uint32_t u; } x; x.f = f;
    uint32_t r = x.u + 0x7fffu + ((x.u >> 16) & 1u);
    return (unsigned short)(r >> 16);
}
__device__ __forceinline__ float b2f(unsigned short u) {
    union { uint32_t u; float f; } x; x.u = ((uint32_t)u) << 16;
    return x.f;
}

#define GLD16(g, l)                                                              \
    __builtin_amdgcn_global_load_lds(                                            \
        (const __attribute__((address_space(1))) void*)(const void*)(g),         \
        (__attribute__((address_space(3))) void*)(void*)(l), 16, 0, 0)

// ---------- bf16 MFMA GEMM: outB = A[M,K]b @ W[N,K]b^T + bias (+relu) ----------
// 128x128 tile, BK=64; grid (M/128, N/128), block 256
__global__ __launch_bounds__(256) void gemm_bf16(
    const unsigned short* __restrict__ A, const unsigned short* __restrict__ Wt,
    const float* __restrict__ bias, unsigned short* __restrict__ outB,
    int M, int N, int K, int relu)
{
    __shared__ __align__(16) unsigned short At[128 * 64];
    __shared__ __align__(16) unsigned short Bt[128 * 64];
    const int tid = threadIdx.x;
    const int lane = tid & 63;
    const int w = tid >> 6;
    const int wm = (w >> 1) * 64, wn = (w & 1) * 64;
    const int lr = lane & 15;
    const int quad = lane >> 4;
    const size_t bm = (size_t)blockIdx.x * 128, bn = (size_t)blockIdx.y * 128;

    frag_cd acc[4][4] = {};

    // staging: thread -> LDS elem i*2048 + tid*8 = (row = i*32 + tid>>3, slot = tid&7)
    // slot holds global chunk (slot ^ (row&7))
    const int ar = tid >> 3;
    const int acs = (((tid & 7) ^ (ar & 7)) << 3);
    const unsigned short* Ag = A  + (bm + ar) * (size_t)K + acs;
    const unsigned short* Bg = Wt + (bn + ar) * (size_t)K + acs;
    unsigned short* Asd = At + w * 512;
    unsigned short* Bsd = Bt + w * 512;

    for (int k0 = 0; k0 < K; k0 += 64) {
        __syncthreads();
#pragma unroll
        for (int i = 0; i < 4; ++i) {
            GLD16(Ag + (size_t)(32 * i) * K + k0, Asd + i * 2048);
            GLD16(Bg + (size_t)(32 * i) * K + k0, Bsd + i * 2048);
        }
        __syncthreads();
#pragma unroll
        for (int kk = 0; kk < 2; ++kk) {
            frag_ab a[4], b[4];
#pragma unroll
            for (int i = 0; i < 4; ++i)
                a[i] = *(const frag_ab*)&At[(wm + i * 16 + lr) * 64 +
                                            ((((kk << 2) | quad) ^ (lr & 7)) << 3)];
#pragma unroll
            for (int j = 0; j < 4; ++j)
                b[j] = *(const frag_ab*)&Bt[(wn + j * 16 + lr) * 64 +
                                            ((((kk << 2) | quad) ^ (lr & 7)) << 3)];
#pragma unroll
            for (int i = 0; i < 4; ++i)
#pragma unroll
                for (int j = 0; j < 4; ++j)
                    acc[i][j] = __builtin_amdgcn_mfma_f32_16x16x32_bf16(a[i], b[j], acc[i][j], 0, 0, 0);
        }
    }

#pragma unroll
    for (int j = 0; j < 4; ++j) {
        const int col = (int)bn + wn + j * 16 + lr;
        const float bv = bias[col];
#pragma unroll
        for (int i = 0; i < 4; ++i) {
            const int rowb = (int)bm + wm + i * 16 + quad * 4;
#pragma unroll
            for (int r = 0; r < 4; ++r) {
                float v = acc[i][j][r] + bv;
                if (relu) v = fmaxf(v, 0.f);
                outB[(size_t)(rowb + r) * N + col] = f2b(v);
            }
        }
    }
}

// ---------- narrow-N residual GEMM: 128x64 tile, BK=64 -------------------------
// outB = A@W^T + bias + residual. resA/resB f32 (rows <8192 / >=8192).
// resA==null: residual = b2f(outB[idx]) (in-place). grid (M/128, N/64).
__global__ __launch_bounds__(256) void gemm_res(
    const unsigned short* __restrict__ A, const unsigned short* __restrict__ Wt,
    const float* __restrict__ bias,
    const float* __restrict__ resA, const float* __restrict__ resB,
    unsigned short* __restrict__ outB, int M, int N, int K)
{
    __shared__ __align__(16) unsigned short At[128 * 64];
    __shared__ __align__(16) unsigned short Bt[64 * 64];
    const int tid = threadIdx.x;
    const int lane = tid & 63;
    const int w = tid >> 6;
    const int wm = w * 32;
    const int lr = lane & 15;
    const int quad = lane >> 4;
    const size_t bm = (size_t)blockIdx.x * 128, bn = (size_t)blockIdx.y * 64;

    frag_cd acc[2][4] = {};

    const int ar = tid >> 3;
    const int acs = (((tid & 7) ^ (ar & 7)) << 3);
    const unsigned short* Ag = A  + (bm + ar) * (size_t)K + acs;
    const unsigned short* Bg = Wt + (bn + ar) * (size_t)K + acs;
    unsigned short* Asd = At + w * 512;
    unsigned short* Bsd = Bt + w * 512;

    for (int k0 = 0; k0 < K; k0 += 64) {
        __syncthreads();
#pragma unroll
        for (int i = 0; i < 4; ++i)
            GLD16(Ag + (size_t)(32 * i) * K + k0, Asd + i * 2048);
#pragma unroll
        for (int i = 0; i < 2; ++i)
            GLD16(Bg + (size_t)(32 * i) * K + k0, Bsd + i * 2048);
        __syncthreads();
#pragma unroll
        for (int kk = 0; kk < 2; ++kk) {
            frag_ab a[2], b[4];
#pragma unroll
            for (int i = 0; i < 2; ++i)
                a[i] = *(const frag_ab*)&At[(wm + i * 16 + lr) * 64 +
                                            ((((kk << 2) | quad) ^ (lr & 7)) << 3)];
#pragma unroll
            for (int j = 0; j < 4; ++j)
                b[j] = *(const frag_ab*)&Bt[(j * 16 + lr) * 64 +
                                            ((((kk << 2) | quad) ^ (lr & 7)) << 3)];
#pragma unroll
            for (int i = 0; i < 2; ++i)
#pragma unroll
                for (int j = 0; j < 4; ++j)
                    acc[i][j] = __builtin_amdgcn_mfma_f32_16x16x32_bf16(a[i], b[j], acc[i][j], 0, 0, 0);
        }
    }

#pragma unroll
    for (int j = 0; j < 4; ++j) {
        const int col = (int)bn + j * 16 + lr;
        const float bv = bias[col];
#pragma unroll
        for (int i = 0; i < 2; ++i) {
            const int rowb = (int)bm + wm + i * 16 + quad * 4;
#pragma unroll
            for (int r = 0; r < 4; ++r) {
                const int row = rowb + r;
                const size_t idx = (size_t)row * N + col;
                float v = acc[i][j][r] + bv;
                if (resA)
                    v += (row < 8192) ? resA[idx] : resB[idx - (size_t)8192 * N];
                else
                    v += b2f(outB[idx]);
                outB[idx] = f2b(v);
            }
        }
    }
}

// -------- merged fp32->bf16 converts + S zero + QKV bias concat --------
__global__ __launch_bounds__(256) void convert_all(
    const float* __restrict__ Wq, const float* __restrict__ Wk,
    const float* __restrict__ Wv, const float* __restrict__ Wo,
    const float* __restrict__ W1, const float* __restrict__ W2,
    const float* __restrict__ question, const float* __restrict__ query,
    const float* __restrict__ bqp, const float* __restrict__ bkp,
    const float* __restrict__ bvp,
    unsigned short* __restrict__ Wqkvb, unsigned short* __restrict__ Wob,
    unsigned short* __restrict__ W1b, unsigned short* __restrict__ W2b,
    unsigned short* __restrict__ Xb, float* __restrict__ S,
    float* __restrict__ bqkv)
{
    const int b = blockIdx.x;
    const float* src; unsigned short* dst; size_t off;
    if (b < 256)        { src = Wq; dst = Wqkvb;          off = (size_t)b * 1024; }
    else if (b < 512)   { src = Wk; dst = Wqkvb + 262144; off = (size_t)(b - 256) * 1024; }
    else if (b < 768)   { src = Wv; dst = Wqkvb + 524288; off = (size_t)(b - 512) * 1024; }
    else if (b < 1024)  { src = Wo; dst = Wob;            off = (size_t)(b - 768) * 1024; }
    else if (b < 2048)  { src = W1; dst = W1b;            off = (size_t)(b - 1024) * 1024; }
    else if (b < 3072)  { src = W2; dst = W2b;            off = (size_t)(b - 2048) * 1024; }
    else if (b < 7168)  { src = question; dst = Xb;       off = (size_t)(b - 3072) * 1024; }
    else if (b < 11264) { src = query; dst = Xb + 4194304; off = (size_t)(b - 7168) * 1024; }
    else if (b < 11392) {
        const size_t idx = ((size_t)(b - 11264) * 256 + threadIdx.x) * 4;
        *(float4*)(S + idx) = make_float4(0.f, 0.f, 0.f, 0.f);
        return;
    } else {
        const int n = (b - 11392) * 256 + threadIdx.x;
        bqkv[n] = (n < 512) ? bqp[n] : (n < 1024) ? bkp[n - 512] : bvp[n - 1024];
        return;
    }
    const size_t idx = off + threadIdx.x * 4;
    float4 v = *(const float4*)(src + idx);
    ushort4 o;
    o.x = f2b(v.x); o.y = f2b(v.y); o.z = f2b(v.z); o.w = f2b(v.w);
    *(ushort4*)(dst + idx) = o;
}

// ------- S[b,h] += sum over both halves of K^T outer V (merged QKV) -------
__global__ __launch_bounds__(256) void s_kernel(
    const unsigned short* __restrict__ QKV, float* __restrict__ S)
{
    const int bh = blockIdx.x, chunk = blockIdx.y;
    const int b = bh >> 3, h = bh & 7;
    __shared__ float Ks[8][64];
    __shared__ float Vs[8][64];
    const int tid = threadIdx.x;
    const int tx = tid & 15, ty = tid >> 4;
    float acc[4][4] = {};
    for (int pass = 0; pass < 2; ++pass) {
        for (int l0 = 0; l0 < 128; l0 += 8) {
#pragma unroll
            for (int it = 0; it < 2; ++it) {
                const int e = tid + it * 256;
                const int rr = e >> 6, cc = e & 63;
                const size_t row = (size_t)pass * 8192 + (size_t)b * Lq + chunk * 128 + l0 + rr;
                Ks[rr][cc] = b2f(QKV[row * 1536 + 512 + h * 64 + cc]);
                Vs[rr][cc] = b2f(QKV[row * 1536 + 1024 + h * 64 + cc]);
            }
            __syncthreads();
#pragma unroll
            for (int rr = 0; rr < 8; ++rr) {
                float kv[4], vv[4];
#pragma unroll
                for (int i = 0; i < 4; ++i) kv[i] = Ks[rr][ty * 4 + i];
#pragma unroll
                for (int j = 0; j < 4; ++j) vv[j] = Vs[rr][tx * 4 + j];
#pragma unroll
                for (int i = 0; i < 4; ++i)
#pragma unroll
                    for (int j = 0; j < 4; ++j)
                        acc[i][j] = fmaf(kv[i], vv[j], acc[i][j]);
            }
            __syncthreads();
        }
    }
#pragma unroll
    for (int i = 0; i < 4; ++i)
#pragma unroll
        for (int j = 0; j < 4; ++j)
            atomicAdd(&S[((size_t)bh * 64 + ty * 4 + i) * 64 + tx * 4 + j], acc[i][j]);
}

// ------- S fp32 -> Sbt bf16, B-operand layout [bh][khalf][n][kj] -------
__global__ __launch_bounds__(256) void sbt_convert(
    const float* __restrict__ S, unsigned short* __restrict__ Sbt)
{
    const int bh = blockIdx.x;
    const float* Sp = S + (size_t)bh * 4096;
    unsigned short* Dp = Sbt + (size_t)bh * 4096;
    const int t = threadIdx.x;
#pragma unroll
    for (int u = 0; u < 16; ++u) {
        const int d = t * 16 + u;
        const int kj = d & 31, n = (d >> 5) & 63, kk = d >> 11;
        Dp[d] = f2b(Sp[(size_t)(kk * 32 + kj) * 64 + n]);
    }
}

// ------- attn = Q @ S_bh via MFMA; block: 128 rows x 64 cols (one head) -------
__global__ __launch_bounds__(256) void attn_mfma(
    const unsigned short* __restrict__ QKV, const unsigned short* __restrict__ Sbt,
    unsigned short* __restrict__ Ob)
{
    __shared__ __align__(16) unsigned short At[2 * 128 * 32];
    __shared__ __align__(16) unsigned short Bt[2 * 64 * 32];
    const int h = blockIdx.x;
    const int rbase = blockIdx.y * 128;
    const int b = (rbase >> 11) & 3;
    const int bh = b * 8 + h;
    const int tid = threadIdx.x;
    const int lane = tid & 63;
    const int w = tid >> 6;
    const int lr = lane & 15;
    const int quad = lane >> 4;

    {
        const int rloc = tid >> 2, c8 = (tid & 3) * 8;
#pragma unroll
        for (int it = 0; it < 4; ++it) {
            const int kk = it & 1, rh = it >> 1;
            const unsigned short* g = QKV +
                ((size_t)rbase + rh * 64 + rloc) * 1536 + h * 64 + kk * 32 + c8;
            GLD16(g, At + kk * 4096 + rh * 2048 + w * 512);
        }
        const unsigned short* Sg = Sbt + (size_t)bh * 4096 + tid * 8;
#pragma unroll
        for (int bi = 0; bi < 2; ++bi)
            GLD16(Sg + bi * 2048, Bt + bi * 2048 + w * 512);
    }
    __syncthreads();

    frag_cd acc[2][4] = {};
#pragma unroll
    for (int kk = 0; kk < 2; ++kk) {
        frag_ab a[2], bfr[4];
#pragma unroll
        for (int i = 0; i < 2; ++i)
            a[i] = *(const frag_ab*)&At[kk * 4096 + (w * 32 + i * 16 + lr) * 32 + quad * 8];
#pragma unroll
        for (int j = 0; j < 4; ++j)
            bfr[j] = *(const frag_ab*)&Bt[kk * 2048 + (j * 16 + lr) * 32 + quad * 8];
#pragma unroll
        for (int i = 0; i < 2; ++i)
#pragma unroll
            for (int j = 0; j < 4; ++j)
                acc[i][j] = __builtin_amdgcn_mfma_f32_16x16x32_bf16(a[i], bfr[j], acc[i][j], 0, 0, 0);
    }

#pragma unroll
    for (int i = 0; i < 2; ++i) {
        const int rowb = rbase + w * 32 + i * 16 + quad * 4;
#pragma unroll
        for (int j = 0; j < 4; ++j) {
            const int col = h * 64 + j * 16 + lr;
#pragma unroll
            for (int r = 0; r < 4; ++r)
                Ob[(size_t)(rowb + r) * 512 + col] = f2b(acc[i][j][r]);
        }
    }
}

// ------- LN over bf16 row (512) in place; wave-shuffle reduction -------
__global__ __launch_bounds__(256) void ln_b16_inplace(
    unsigned short* __restrict__ Y, const float* __restrict__ g,
    const float* __restrict__ bta)
{
    __shared__ float part[8];
    const int row = blockIdx.x;
    const int t = threadIdx.x;
    const int w = t >> 6;
    unsigned short* yr = Y + (size_t)row * Dq;
    const float v0 = b2f(yr[t]), v1 = b2f(yr[t + 256]);
    float s = v0 + v1;
#pragma unroll
    for (int off = 32; off; off >>= 1) s += __shfl_xor(s, off, 64);
    if ((t & 63) == 0) part[w] = s;
    __syncthreads();
    const float mean = (part[0] + part[1] + part[2] + part[3]) * (1.f / Dq);
    const float d0 = v0 - mean, d1 = v1 - mean;
    float q = d0 * d0 + d1 * d1;
#pragma unroll
    for (int off = 32; off; off >>= 1) q += __shfl_xor(q, off, 64);
    if ((t & 63) == 0) part[4 + w] = q;
    __syncthreads();
    const float rstd = rsqrtf((part[4] + part[5] + part[6] + part[7]) * (1.f / Dq) + 1e-5f);
    yr[t] = f2b(d0 * rstd * g[t] + bta[t]);
    yr[t + 256] = f2b(d1 * rstd * g[t + 256] + bta[t + 256]);
}

// ------- LN over bf16 row -> out f32 half-columns (merged rows) -------
__global__ __launch_bounds__(256) void ln_b16_out(
    const unsigned short* __restrict__ Y, const float* __restrict__ g,
    const float* __restrict__ bta, float* __restrict__ out)
{
    __shared__ float part[8];
    const int row = blockIdx.x;
    const int t = threadIdx.x;
    const int w = t >> 6;
    const unsigned short* yr = Y + (size_t)row * Dq;
    const float v0 = b2f(yr[t]), v1 = b2f(yr[t + 256]);
    float s = v0 + v1;
#pragma unroll
    for (int off = 32; off; off >>= 1) s += __shfl_xor(s, off, 64);
    if ((t & 63) == 0) part[w] = s;
    __syncthreads();
    const float mean = (part[0] + part[1] + part[2] + part[3]) * (1.f / Dq);
    const float d0 = v0 - mean, d1 = v1 - mean;
    float q = d0 * d0 + d1 * d1;
#pragma unroll
    for (int off = 32; off; off >>= 1) q += __shfl_xor(q, off, 64);
    if ((t & 63) == 0) part[4 + w] = q;
    __syncthreads();
    const float rstd = rsqrtf((part[4] + part[5] + part[6] + part[7]) * (1.f / Dq) + 1e-5f);
    const int half = row >> 13, br = row & 8191;
    float* orow = out + (size_t)br * 1024 + half * 512;
    orow[t] = d0 * rstd * g[t] + bta[t];
    orow[t + 256] = d1 * rstd * g[t + 256] + bta[t + 256];
}

extern "C" void kernel_launch(void* const* d_in, const int* in_sizes, int n_in,
                              void* d_out, int out_size, void* d_ws, size_t ws_size,
                              hipStream_t stream)
{
    const float* question = (const float*)d_in[0];
    const float* query    = (const float*)d_in[1];
    const float* Wq = (const float*)d_in[2];  const float* bqp = (const float*)d_in[3];
    const float* Wk = (const float*)d_in[4];  const float* bkp = (const float*)d_in[5];
    const float* Wv = (const float*)d_in[6];  const float* bvp = (const float*)d_in[7];
    const float* Wo = (const float*)d_in[8];  const float* bo  = (const float*)d_in[9];
    const float* ln_g = (const float*)d_in[10]; const float* ln_b = (const float*)d_in[11];
    const float* W1 = (const float*)d_in[12]; const float* b1 = (const float*)d_in[13];
    const float* W2 = (const float*)d_in[14]; const float* b2 = (const float*)d_in[15];
    float* out = (float*)d_out;
    char* ws = (char*)d_ws;

    // ---- workspace (~87 MiB) ----
    unsigned short* QKVb  = (unsigned short*)(ws);
    unsigned short* attnb = (unsigned short*)(ws + 48 * MiBu);
    unsigned short* Xb    = (unsigned short*)(ws + 64 * MiBu);
    unsigned short* xbuf  = (unsigned short*)(ws + 64 * MiBu);  // y0b -> xb -> y
    unsigned short* hb    = (unsigned short*)(ws);              // [16384,2048] bf16
    float* S = (float*)(ws + 80 * MiBu);
    char* wp = ws + 80 * MiBu + 524288;
    unsigned short* Wqkvb = (unsigned short*)wp;  wp += 1536 * 512 * 2;
    unsigned short* Wob   = (unsigned short*)wp;  wp += 512 * 512 * 2;
    unsigned short* W1b   = (unsigned short*)wp;  wp += 2048 * 512 * 2;
    unsigned short* W2b   = (unsigned short*)wp;  wp += 512 * 2048 * 2;
    unsigned short* Sbt   = (unsigned short*)wp;  wp += 32 * 4096 * 2;
    float* bqkv           = (float*)wp;

    dim3 blk(256);

    convert_all<<<11398, blk, 0, stream>>>(Wq, Wk, Wv, Wo, W1, W2, question, query,
                                           bqp, bkp, bvp,
                                           Wqkvb, Wob, W1b, W2b, Xb, S, bqkv);

    // QKV: [16384,512]@[1536,512]^T -> bf16; M-major grid (1536 blocks)
    gemm_bf16<<<dim3(128, 12), blk, 0, stream>>>(Xb, Wqkvb, bqkv, QKVb,
                                                 Mrows, 1536, 512, 0);

    // S accumulation (fp32) -> bf16 B-layout; attn via MFMA (1024 blocks)
    s_kernel<<<dim3(32, 16), blk, 0, stream>>>(QKVb, S);
    sbt_convert<<<32, blk, 0, stream>>>(S, Sbt);
    attn_mfma<<<dim3(8, 128), blk, 0, stream>>>(QKVb, Sbt, attnb);

    // o-proj + residual(inputs) + bo -> bf16 y0b (128x64 tiles, 1024 blocks)
    gemm_res<<<dim3(128, 8), blk, 0, stream>>>(attnb, Wob, bo, question, query,
                                               xbuf, Mrows, 512, 512);

    // LN1 in place: xb = LN(y0b)
    ln_b16_inplace<<<Mrows, blk, 0, stream>>>(xbuf, ln_g, ln_b);

    // FFN1 full-M: h = relu(xb @ W1^T + b1) -> bf16 [16384,2048] (2048 blocks)
    gemm_bf16<<<dim3(128, 16), blk, 0, stream>>>(xbuf, W1b, b1, hb,
                                                 Mrows, PFq, 512, 1);

    // FFN2 full-M, K=2048: y = h @ W2^T + b2 + xb, bf16 in place (1024 blocks)
    gemm_res<<<dim3(128, 8), blk, 0, stream>>>(hb, W2b, b2, nullptr, nullptr,
                                               xbuf, Mrows, 512, PFq);

    // LN2 -> out halves
    ln_b16_out<<<Mrows, blk, 0, stream>>>(xbuf, ln_g, ln_b, out);
}

// Round 9
// 343.807 us; speedup vs baseline: 1.4002x; 1.1362x over previous
//
#include <hip/hip_runtime.h>
#include <stdint.h>

// CrossAttention via linear-attention algebra, both halves merged to M=16384:
//   S = K1^T V1 + K2^T V2 (per b,h; 64x64), shared by both halves.
//   attn = Q @ S ; x = LN(inp + attn@Wo^T + bo) ; out = LN(x + FF(x))
// bf16 MFMA GEMMs, BK=64, XOR-swizzled LDS staging (R8: 0 bank conflicts).
// R9: LDS-staged coalesced epilogues — R8 showed 2.25x HBM write amplification
// from scattered 2-byte stores (WRITE 144MB on 64MB output). Waves dump C to
// LDS (reusing At/Bt after a barrier), read back 16B/lane, store 64B sectors.
// Residual adds happen post-LDS so reads coalesce too.

#define Bq 4
#define Lq 2048
#define Dq 512
#define PFq 2048
#define Mrows 16384
#define MiBu 1048576ull

typedef __attribute__((ext_vector_type(8))) short frag_ab;
typedef __attribute__((ext_vector_type(4))) float frag_cd;
typedef __attribute__((ext_vector_type(8))) unsigned short ushort8v;

__device__ __forceinline__ unsigned short f2b(float f) {
    union { float f; uint32_t u; } x; x.f = f;
    uint32_t r = x.u + 0x7fffu + ((x.u >> 16) & 1u);
    return (unsigned short)(r >> 16);
}
__device__ __forceinline__ float b2f(unsigned short u) {
    union { uint32_t u; float f; } x; x.u = ((uint32_t)u) << 16;
    return x.f;
}

#define GLD16(g, l)                                                              \
    __builtin_amdgcn_global_load_lds(                                            \
        (const __attribute__((address_space(1))) void*)(const void*)(g),         \
        (__attribute__((address_space(3))) void*)(void*)(l), 16, 0, 0)

// ---------- bf16 MFMA GEMM: outB = A[M,K]b @ W[N,K]b^T + bias (+relu) ----------
// 128x128 tile, BK=64; grid (M/128, N/128), block 256
__global__ __launch_bounds__(256) void gemm_bf16(
    const unsigned short* __restrict__ A, const unsigned short* __restrict__ Wt,
    const float* __restrict__ bias, unsigned short* __restrict__ outB,
    int M, int N, int K, int relu)
{
    __shared__ __align__(16) unsigned short Sh[2 * 128 * 64];
    unsigned short* At = Sh;
    unsigned short* Bt = Sh + 128 * 64;
    const int tid = threadIdx.x;
    const int lane = tid & 63;
    const int w = tid >> 6;
    const int wm = (w >> 1) * 64, wn = (w & 1) * 64;
    const int lr = lane & 15;
    const int quad = lane >> 4;
    const size_t bm = (size_t)blockIdx.x * 128, bn = (size_t)blockIdx.y * 128;

    frag_cd acc[4][4] = {};

    const int ar = tid >> 3;
    const int acs = (((tid & 7) ^ (ar & 7)) << 3);
    const unsigned short* Ag = A  + (bm + ar) * (size_t)K + acs;
    const unsigned short* Bg = Wt + (bn + ar) * (size_t)K + acs;
    unsigned short* Asd = At + w * 512;
    unsigned short* Bsd = Bt + w * 512;

    for (int k0 = 0; k0 < K; k0 += 64) {
        __syncthreads();
#pragma unroll
        for (int i = 0; i < 4; ++i) {
            GLD16(Ag + (size_t)(32 * i) * K + k0, Asd + i * 2048);
            GLD16(Bg + (size_t)(32 * i) * K + k0, Bsd + i * 2048);
        }
        __syncthreads();
#pragma unroll
        for (int kk = 0; kk < 2; ++kk) {
            frag_ab a[4], b[4];
#pragma unroll
            for (int i = 0; i < 4; ++i)
                a[i] = *(const frag_ab*)&At[(wm + i * 16 + lr) * 64 +
                                            ((((kk << 2) | quad) ^ (lr & 7)) << 3)];
#pragma unroll
            for (int j = 0; j < 4; ++j)
                b[j] = *(const frag_ab*)&Bt[(wn + j * 16 + lr) * 64 +
                                            ((((kk << 2) | quad) ^ (lr & 7)) << 3)];
#pragma unroll
            for (int i = 0; i < 4; ++i)
#pragma unroll
                for (int j = 0; j < 4; ++j)
                    acc[i][j] = __builtin_amdgcn_mfma_f32_16x16x32_bf16(a[i], b[j], acc[i][j], 0, 0, 0);
        }
    }

    // LDS-staged epilogue: wave w owns Sh[w*4096 .. +4096) = 64x64 bf16
    __syncthreads();
    unsigned short* Cs = Sh + w * 4096;
#pragma unroll
    for (int j = 0; j < 4; ++j) {
        const float bv = bias[(int)bn + wn + j * 16 + lr];
#pragma unroll
        for (int i = 0; i < 4; ++i)
#pragma unroll
            for (int r = 0; r < 4; ++r) {
                float v = acc[i][j][r] + bv;
                if (relu) v = fmaxf(v, 0.f);
                Cs[(i * 16 + quad * 4 + r) * 64 + j * 16 + lr] = f2b(v);
            }
    }
    const int rl = lane >> 3;            // 0..7
    const int c8 = (lane & 7) * 8;       // col chunk base
#pragma unroll
    for (int k = 0; k < 8; ++k) {
        const int row = rl + k * 8;
        ushort8v val = *(const ushort8v*)&Cs[row * 64 + c8];
        *(ushort8v*)(outB + (size_t)(bm + wm + row) * N + bn + wn + c8) = val;
    }
}

// ---------- narrow-N residual GEMM: 128x64 tile, BK=64 -------------------------
// outB = A@W^T + bias + residual. resA/resB f32 (rows <8192 / >=8192).
// resA==null: residual = b2f(outB[idx]) (in-place). grid (M/128, N/64).
__global__ __launch_bounds__(256) void gemm_res(
    const unsigned short* __restrict__ A, const unsigned short* __restrict__ Wt,
    const float* __restrict__ bias,
    const float* __restrict__ resA, const float* __restrict__ resB,
    unsigned short* __restrict__ outB, int M, int N, int K)
{
    __shared__ __align__(16) unsigned short Sh[128 * 64 + 64 * 64];
    unsigned short* At = Sh;
    unsigned short* Bt = Sh + 128 * 64;
    const int tid = threadIdx.x;
    const int lane = tid & 63;
    const int w = tid >> 6;
    const int wm = w * 32;
    const int lr = lane & 15;
    const int quad = lane >> 4;
    const size_t bm = (size_t)blockIdx.x * 128, bn = (size_t)blockIdx.y * 64;

    frag_cd acc[2][4] = {};

    const int ar = tid >> 3;
    const int acs = (((tid & 7) ^ (ar & 7)) << 3);
    const unsigned short* Ag = A  + (bm + ar) * (size_t)K + acs;
    const unsigned short* Bg = Wt + (bn + ar) * (size_t)K + acs;
    unsigned short* Asd = At + w * 512;
    unsigned short* Bsd = Bt + w * 512;

    for (int k0 = 0; k0 < K; k0 += 64) {
        __syncthreads();
#pragma unroll
        for (int i = 0; i < 4; ++i)
            GLD16(Ag + (size_t)(32 * i) * K + k0, Asd + i * 2048);
#pragma unroll
        for (int i = 0; i < 2; ++i)
            GLD16(Bg + (size_t)(32 * i) * K + k0, Bsd + i * 2048);
        __syncthreads();
#pragma unroll
        for (int kk = 0; kk < 2; ++kk) {
            frag_ab a[2], b[4];
#pragma unroll
            for (int i = 0; i < 2; ++i)
                a[i] = *(const frag_ab*)&At[(wm + i * 16 + lr) * 64 +
                                            ((((kk << 2) | quad) ^ (lr & 7)) << 3)];
#pragma unroll
            for (int j = 0; j < 4; ++j)
                b[j] = *(const frag_ab*)&Bt[(j * 16 + lr) * 64 +
                                            ((((kk << 2) | quad) ^ (lr & 7)) << 3)];
#pragma unroll
            for (int i = 0; i < 2; ++i)
#pragma unroll
                for (int j = 0; j < 4; ++j)
                    acc[i][j] = __builtin_amdgcn_mfma_f32_16x16x32_bf16(a[i], b[j], acc[i][j], 0, 0, 0);
        }
    }

    // LDS-staged epilogue: wave w owns Sh[w*2048 .. +2048) = 32x64 bf16
    __syncthreads();
    unsigned short* Cs = Sh + w * 2048;
#pragma unroll
    for (int j = 0; j < 4; ++j) {
        const float bv = bias[(int)bn + j * 16 + lr];
#pragma unroll
        for (int i = 0; i < 2; ++i)
#pragma unroll
            for (int r = 0; r < 4; ++r)
                Cs[(i * 16 + quad * 4 + r) * 64 + j * 16 + lr] = f2b(acc[i][j][r] + bv);
    }
    const int rl = lane >> 3;
    const int c8 = (lane & 7) * 8;
#pragma unroll
    for (int k = 0; k < 4; ++k) {
        const int row = rl + k * 8;
        const int grow = (int)bm + wm + row;
        const size_t idx = (size_t)grow * N + bn + c8;
        ushort8v val = *(const ushort8v*)&Cs[row * 64 + c8];
        float vv[8];
#pragma unroll
        for (int t = 0; t < 8; ++t) vv[t] = b2f(val[t]);
        if (resA) {
            const float* rp = (grow < 8192) ? resA + idx : resB + idx - (size_t)8192 * N;
            float4 ra = *(const float4*)(rp);
            float4 rb = *(const float4*)(rp + 4);
            vv[0] += ra.x; vv[1] += ra.y; vv[2] += ra.z; vv[3] += ra.w;
            vv[4] += rb.x; vv[5] += rb.y; vv[6] += rb.z; vv[7] += rb.w;
        } else {
            ushort8v old = *(const ushort8v*)(outB + idx);
#pragma unroll
            for (int t = 0; t < 8; ++t) vv[t] += b2f(old[t]);
        }
        ushort8v o;
#pragma unroll
        for (int t = 0; t < 8; ++t) o[t] = f2b(vv[t]);
        *(ushort8v*)(outB + idx) = o;
    }
}

// -------- merged fp32->bf16 converts + S zero + QKV bias concat --------
__global__ __launch_bounds__(256) void convert_all(
    const float* __restrict__ Wq, const float* __restrict__ Wk,
    const float* __restrict__ Wv, const float* __restrict__ Wo,
    const float* __restrict__ W1, const float* __restrict__ W2,
    const float* __restrict__ question, const float* __restrict__ query,
    const float* __restrict__ bqp, const float* __restrict__ bkp,
    const float* __restrict__ bvp,
    unsigned short* __restrict__ Wqkvb, unsigned short* __restrict__ Wob,
    unsigned short* __restrict__ W1b, unsigned short* __restrict__ W2b,
    unsigned short* __restrict__ Xb, float* __restrict__ S,
    float* __restrict__ bqkv)
{
    const int b = blockIdx.x;
    const float* src; unsigned short* dst; size_t off;
    if (b < 256)        { src = Wq; dst = Wqkvb;          off = (size_t)b * 1024; }
    else if (b < 512)   { src = Wk; dst = Wqkvb + 262144; off = (size_t)(b - 256) * 1024; }
    else if (b < 768)   { src = Wv; dst = Wqkvb + 524288; off = (size_t)(b - 512) * 1024; }
    else if (b < 1024)  { src = Wo; dst = Wob;            off = (size_t)(b - 768) * 1024; }
    else if (b < 2048)  { src = W1; dst = W1b;            off = (size_t)(b - 1024) * 1024; }
    else if (b < 3072)  { src = W2; dst = W2b;            off = (size_t)(b - 2048) * 1024; }
    else if (b < 7168)  { src = question; dst = Xb;       off = (size_t)(b - 3072) * 1024; }
    else if (b < 11264) { src = query; dst = Xb + 4194304; off = (size_t)(b - 7168) * 1024; }
    else if (b < 11392) {
        const size_t idx = ((size_t)(b - 11264) * 256 + threadIdx.x) * 4;
        *(float4*)(S + idx) = make_float4(0.f, 0.f, 0.f, 0.f);
        return;
    } else {
        const int n = (b - 11392) * 256 + threadIdx.x;
        bqkv[n] = (n < 512) ? bqp[n] : (n < 1024) ? bkp[n - 512] : bvp[n - 1024];
        return;
    }
    const size_t idx = off + threadIdx.x * 4;
    float4 v = *(const float4*)(src + idx);
    ushort4 o;
    o.x = f2b(v.x); o.y = f2b(v.y); o.z = f2b(v.z); o.w = f2b(v.w);
    *(ushort4*)(dst + idx) = o;
}

// ------- S[b,h] += sum over both halves of K^T outer V (merged QKV) -------
__global__ __launch_bounds__(256) void s_kernel(
    const unsigned short* __restrict__ QKV, float* __restrict__ S)
{
    const int bh = blockIdx.x, chunk = blockIdx.y;
    const int b = bh >> 3, h = bh & 7;
    __shared__ float Ks[8][64];
    __shared__ float Vs[8][64];
    const int tid = threadIdx.x;
    const int tx = tid & 15, ty = tid >> 4;
    float acc[4][4] = {};
    for (int pass = 0; pass < 2; ++pass) {
        for (int l0 = 0; l0 < 128; l0 += 8) {
#pragma unroll
            for (int it = 0; it < 2; ++it) {
                const int e = tid + it * 256;
                const int rr = e >> 6, cc = e & 63;
                const size_t row = (size_t)pass * 8192 + (size_t)b * Lq + chunk * 128 + l0 + rr;
                Ks[rr][cc] = b2f(QKV[row * 1536 + 512 + h * 64 + cc]);
                Vs[rr][cc] = b2f(QKV[row * 1536 + 1024 + h * 64 + cc]);
            }
            __syncthreads();
#pragma unroll
            for (int rr = 0; rr < 8; ++rr) {
                float kv[4], vv[4];
#pragma unroll
                for (int i = 0; i < 4; ++i) kv[i] = Ks[rr][ty * 4 + i];
#pragma unroll
                for (int j = 0; j < 4; ++j) vv[j] = Vs[rr][tx * 4 + j];
#pragma unroll
                for (int i = 0; i < 4; ++i)
#pragma unroll
                    for (int j = 0; j < 4; ++j)
                        acc[i][j] = fmaf(kv[i], vv[j], acc[i][j]);
            }
            __syncthreads();
        }
    }
#pragma unroll
    for (int i = 0; i < 4; ++i)
#pragma unroll
        for (int j = 0; j < 4; ++j)
            atomicAdd(&S[((size_t)bh * 64 + ty * 4 + i) * 64 + tx * 4 + j], acc[i][j]);
}

// ------- S fp32 -> Sbt bf16, B-operand layout [bh][khalf][n][kj] -------
__global__ __launch_bounds__(256) void sbt_convert(
    const float* __restrict__ S, unsigned short* __restrict__ Sbt)
{
    const int bh = blockIdx.x;
    const float* Sp = S + (size_t)bh * 4096;
    unsigned short* Dp = Sbt + (size_t)bh * 4096;
    const int t = threadIdx.x;
#pragma unroll
    for (int u = 0; u < 16; ++u) {
        const int d = t * 16 + u;
        const int kj = d & 31, n = (d >> 5) & 63, kk = d >> 11;
        Dp[d] = f2b(Sp[(size_t)(kk * 32 + kj) * 64 + n]);
    }
}

// ------- attn = Q @ S_bh via MFMA; block: 128 rows x 64 cols (one head) -------
__global__ __launch_bounds__(256) void attn_mfma(
    const unsigned short* __restrict__ QKV, const unsigned short* __restrict__ Sbt,
    unsigned short* __restrict__ Ob)
{
    __shared__ __align__(16) unsigned short Sh[2 * 128 * 32 + 2 * 64 * 32];
    unsigned short* At = Sh;
    unsigned short* Bt = Sh + 2 * 128 * 32;
    const int h = blockIdx.x;
    const int rbase = blockIdx.y * 128;
    const int b = (rbase >> 11) & 3;
    const int bh = b * 8 + h;
    const int tid = threadIdx.x;
    const int lane = tid & 63;
    const int w = tid >> 6;
    const int lr = lane & 15;
    const int quad = lane >> 4;

    {
        const int rloc = tid >> 2, c8 = (tid & 3) * 8;
#pragma unroll
        for (int it = 0; it < 4; ++it) {
            const int kk = it & 1, rh = it >> 1;
            const unsigned short* g = QKV +
                ((size_t)rbase + rh * 64 + rloc) * 1536 + h * 64 + kk * 32 + c8;
            GLD16(g, At + kk * 4096 + rh * 2048 + w * 512);
        }
        const unsigned short* Sg = Sbt + (size_t)bh * 4096 + tid * 8;
#pragma unroll
        for (int bi = 0; bi < 2; ++bi)
            GLD16(Sg + bi * 2048, Bt + bi * 2048 + w * 512);
    }
    __syncthreads();

    frag_cd acc[2][4] = {};
#pragma unroll
    for (int kk = 0; kk < 2; ++kk) {
        frag_ab a[2], bfr[4];
#pragma unroll
        for (int i = 0; i < 2; ++i)
            a[i] = *(const frag_ab*)&At[kk * 4096 + (w * 32 + i * 16 + lr) * 32 + quad * 8];
#pragma unroll
        for (int j = 0; j < 4; ++j)
            bfr[j] = *(const frag_ab*)&Bt[kk * 2048 + (j * 16 + lr) * 32 + quad * 8];
#pragma unroll
        for (int i = 0; i < 2; ++i)
#pragma unroll
            for (int j = 0; j < 4; ++j)
                acc[i][j] = __builtin_amdgcn_mfma_f32_16x16x32_bf16(a[i], bfr[j], acc[i][j], 0, 0, 0);
    }

    // LDS-staged epilogue: wave w owns Sh[w*2048 .. +2048) = 32x64 bf16
    __syncthreads();
    unsigned short* Cs = Sh + w * 2048;
#pragma unroll
    for (int i = 0; i < 2; ++i)
#pragma unroll
        for (int j = 0; j < 4; ++j)
#pragma unroll
            for (int r = 0; r < 4; ++r)
                Cs[(i * 16 + quad * 4 + r) * 64 + j * 16 + lr] = f2b(acc[i][j][r]);
    const int rl = lane >> 3;
    const int c8o = (lane & 7) * 8;
#pragma unroll
    for (int k = 0; k < 4; ++k) {
        const int row = rl + k * 8;
        ushort8v val = *(const ushort8v*)&Cs[row * 64 + c8o];
        *(ushort8v*)(Ob + (size_t)(rbase + w * 32 + row) * 512 + h * 64 + c8o) = val;
    }
}

// ------- LN over bf16 row (512) in place; wave-shuffle reduction -------
__global__ __launch_bounds__(256) void ln_b16_inplace(
    unsigned short* __restrict__ Y, const float* __restrict__ g,
    const float* __restrict__ bta)
{
    __shared__ float part[8];
    const int row = blockIdx.x;
    const int t = threadIdx.x;
    const int w = t >> 6;
    unsigned short* yr = Y + (size_t)row * Dq;
    const float v0 = b2f(yr[t]), v1 = b2f(yr[t + 256]);
    float s = v0 + v1;
#pragma unroll
    for (int off = 32; off; off >>= 1) s += __shfl_xor(s, off, 64);
    if ((t & 63) == 0) part[w] = s;
    __syncthreads();
    const float mean = (part[0] + part[1] + part[2] + part[3]) * (1.f / Dq);
    const float d0 = v0 - mean, d1 = v1 - mean;
    float q = d0 * d0 + d1 * d1;
#pragma unroll
    for (int off = 32; off; off >>= 1) q += __shfl_xor(q, off, 64);
    if ((t & 63) == 0) part[4 + w] = q;
    __syncthreads();
    const float rstd = rsqrtf((part[4] + part[5] + part[6] + part[7]) * (1.f / Dq) + 1e-5f);
    yr[t] = f2b(d0 * rstd * g[t] + bta[t]);
    yr[t + 256] = f2b(d1 * rstd * g[t + 256] + bta[t + 256]);
}

// ------- LN over bf16 row -> out f32 half-columns (merged rows) -------
__global__ __launch_bounds__(256) void ln_b16_out(
    const unsigned short* __restrict__ Y, const float* __restrict__ g,
    const float* __restrict__ bta, float* __restrict__ out)
{
    __shared__ float part[8];
    const int row = blockIdx.x;
    const int t = threadIdx.x;
    const int w = t >> 6;
    const unsigned short* yr = Y + (size_t)row * Dq;
    const float v0 = b2f(yr[t]), v1 = b2f(yr[t + 256]);
    float s = v0 + v1;
#pragma unroll
    for (int off = 32; off; off >>= 1) s += __shfl_xor(s, off, 64);
    if ((t & 63) == 0) part[w] = s;
    __syncthreads();
    const float mean = (part[0] + part[1] + part[2] + part[3]) * (1.f / Dq);
    const float d0 = v0 - mean, d1 = v1 - mean;
    float q = d0 * d0 + d1 * d1;
#pragma unroll
    for (int off = 32; off; off >>= 1) q += __shfl_xor(q, off, 64);
    if ((t & 63) == 0) part[4 + w] = q;
    __syncthreads();
    const float rstd = rsqrtf((part[4] + part[5] + part[6] + part[7]) * (1.f / Dq) + 1e-5f);
    const int half = row >> 13, br = row & 8191;
    float* orow = out + (size_t)br * 1024 + half * 512;
    orow[t] = d0 * rstd * g[t] + bta[t];
    orow[t + 256] = d1 * rstd * g[t + 256] + bta[t + 256];
}

extern "C" void kernel_launch(void* const* d_in, const int* in_sizes, int n_in,
                              void* d_out, int out_size, void* d_ws, size_t ws_size,
                              hipStream_t stream)
{
    const float* question = (const float*)d_in[0];
    const float* query    = (const float*)d_in[1];
    const float* Wq = (const float*)d_in[2];  const float* bqp = (const float*)d_in[3];
    const float* Wk = (const float*)d_in[4];  const float* bkp = (const float*)d_in[5];
    const float* Wv = (const float*)d_in[6];  const float* bvp = (const float*)d_in[7];
    const float* Wo = (const float*)d_in[8];  const float* bo  = (const float*)d_in[9];
    const float* ln_g = (const float*)d_in[10]; const float* ln_b = (const float*)d_in[11];
    const float* W1 = (const float*)d_in[12]; const float* b1 = (const float*)d_in[13];
    const float* W2 = (const float*)d_in[14]; const float* b2 = (const float*)d_in[15];
    float* out = (float*)d_out;
    char* ws = (char*)d_ws;

    // ---- workspace (~87 MiB) ----
    unsigned short* QKVb  = (unsigned short*)(ws);
    unsigned short* attnb = (unsigned short*)(ws + 48 * MiBu);
    unsigned short* Xb    = (unsigned short*)(ws + 64 * MiBu);
    unsigned short* xbuf  = (unsigned short*)(ws + 64 * MiBu);  // y0b -> xb -> y
    unsigned short* hb    = (unsigned short*)(ws);              // [16384,2048] bf16
    float* S = (float*)(ws + 80 * MiBu);
    char* wp = ws + 80 * MiBu + 524288;
    unsigned short* Wqkvb = (unsigned short*)wp;  wp += 1536 * 512 * 2;
    unsigned short* Wob   = (unsigned short*)wp;  wp += 512 * 512 * 2;
    unsigned short* W1b   = (unsigned short*)wp;  wp += 2048 * 512 * 2;
    unsigned short* W2b   = (unsigned short*)wp;  wp += 512 * 2048 * 2;
    unsigned short* Sbt   = (unsigned short*)wp;  wp += 32 * 4096 * 2;
    float* bqkv           = (float*)wp;

    dim3 blk(256);

    convert_all<<<11398, blk, 0, stream>>>(Wq, Wk, Wv, Wo, W1, W2, question, query,
                                           bqp, bkp, bvp,
                                           Wqkvb, Wob, W1b, W2b, Xb, S, bqkv);

    // QKV: [16384,512]@[1536,512]^T -> bf16; M-major grid (1536 blocks)
    gemm_bf16<<<dim3(128, 12), blk, 0, stream>>>(Xb, Wqkvb, bqkv, QKVb,
                                                 Mrows, 1536, 512, 0);

    // S accumulation (fp32) -> bf16 B-layout; attn via MFMA (1024 blocks)
    s_kernel<<<dim3(32, 16), blk, 0, stream>>>(QKVb, S);
    sbt_convert<<<32, blk, 0, stream>>>(S, Sbt);
    attn_mfma<<<dim3(8, 128), blk, 0, stream>>>(QKVb, Sbt, attnb);

    // o-proj + residual(inputs) + bo -> bf16 y0b (128x64 tiles, 1024 blocks)
    gemm_res<<<dim3(128, 8), blk, 0, stream>>>(attnb, Wob, bo, question, query,
                                               xbuf, Mrows, 512, 512);

    // LN1 in place: xb = LN(y0b)
    ln_b16_inplace<<<Mrows, blk, 0, stream>>>(xbuf, ln_g, ln_b);

    // FFN1 full-M: h = relu(xb @ W1^T + b1) -> bf16 [16384,2048] (2048 blocks)
    gemm_bf16<<<dim3(128, 16), blk, 0, stream>>>(xbuf, W1b, b1, hb,
                                                 Mrows, PFq, 512, 1);

    // FFN2 full-M, K=2048: y = h @ W2^T + b2 + xb, bf16 in place (1024 blocks)
    gemm_res<<<dim3(128, 8), blk, 0, stream>>>(hb, W2b, b2, nullptr, nullptr,
                                               xbuf, Mrows, 512, PFq);

    // LN2 -> out halves
    ln_b16_out<<<Mrows, blk, 0, stream>>>(xbuf, ln_g, ln_b, out);
}